// Round 17
// baseline (274.175 us; speedup 1.0000x reference)
//
#include <hip/hip_runtime.h>
#include <hip/hip_bf16.h>
#include <math.h>

#define D 128
#define H 8
#define DH 16
#define SCAN_CHUNK 1024

typedef __attribute__((ext_vector_type(8))) short bf16x8;
typedef __attribute__((ext_vector_type(4))) float f32x4;

__device__ __forceinline__ float bf2f(ushort u) {
    unsigned int x = ((unsigned int)u) << 16;
    float f;
    __builtin_memcpy(&f, &x, 4);
    return f;
}
__device__ __forceinline__ ushort f2bf(float f) {
    __hip_bfloat16 h = __float2bfloat16(f);
    ushort u;
    __builtin_memcpy(&u, &h, 2);
    return u;
}

// load 8 consecutive f32 and split into bf16 hi/lo fragments in-register
__device__ __forceinline__ void load_split8(const float* src, bf16x8* hi, bf16x8* lo) {
    float4 a = *(const float4*)src;
    float4 b = *(const float4*)(src + 4);
    float xs[8] = {a.x, a.y, a.z, a.w, b.x, b.y, b.z, b.w};
    short hv[8], lv[8];
    #pragma unroll
    for (int i = 0; i < 8; ++i) {
        ushort hb = f2bf(xs[i]);
        hv[i] = (short)hb;
        lv[i] = (short)f2bf(xs[i] - bf2f(hb));
    }
    *hi = (bf16x8){hv[0], hv[1], hv[2], hv[3], hv[4], hv[5], hv[6], hv[7]};
    *lo = (bf16x8){lv[0], lv[1], lv[2], lv[3], lv[4], lv[5], lv[6], lv[7]};
}

// Stage a 128x128 bf16 matrix (32KB) global -> LDS, XOR-swizzled 16B slots.
// 256-thread version: 2048 slots, 8 per thread.
#define STAGE_W(SRC, LDSBUF)                                              \
    {                                                                      \
        _Pragma("unroll")                                                  \
        for (int it_ = 0; it_ < 8; ++it_) {                                \
            int idx16_ = t + it_ * 256;                                    \
            int row_ = idx16_ >> 4, c16_ = idx16_ & 15;                    \
            int d_ = (row_ << 7) + ((c16_ ^ (row_ & 7)) << 3);             \
            *(bf16x8*)((LDSBUF) + d_) = *(const bf16x8*)((SRC) + idx16_ * 8); \
        }                                                                  \
    }

#define LOAD_A(SRCH, SRCL, BASE, AH, AL)                                   \
    _Pragma("unroll")                                                      \
    for (int kk_ = 0; kk_ < 4; ++kk_) {                                    \
        AH[kk_] = *(const bf16x8*)((SRCH) + (BASE) + kk_ * 32);            \
        AL[kk_] = *(const bf16x8*)((SRCL) + (BASE) + kk_ * 32);            \
    }

// 16-rows-per-wave MFMA tile, bf16 weights: acc += (Ah+Al)*Bh
#define TILE_MFMA16(AH, AL, WH, ACC)                                       \
    _Pragma("unroll")                                                      \
    for (int kk = 0; kk < 4; ++kk) {                                       \
        _Pragma("unroll")                                                  \
        for (int n = 0; n < 8; ++n) {                                      \
            int rn = n * 16 + l15;                                         \
            int off = (rn << 7) + (((l4 + kk * 4) ^ (rn & 7)) << 3);       \
            bf16x8 bh = *(const bf16x8*)((WH) + off);                      \
            ACC[n] = __builtin_amdgcn_mfma_f32_16x16x32_bf16(AH[kk], bh, ACC[n], 0, 0, 0); \
            ACC[n] = __builtin_amdgcn_mfma_f32_16x16x32_bf16(AL[kk], bh, ACC[n], 0, 0, 0); \
        }                                                                  \
    }

// ---------------- prep_w: transpose 6 weight matrices (bf16) + zero count ---

__global__ __launch_bounds__(256) void prep_w_kernel(
    const float* __restrict__ w0, const float* __restrict__ w1,
    const float* __restrict__ w2, const float* __restrict__ w3,
    const float* __restrict__ w4, const float* __restrict__ w5,
    ushort* __restrict__ wth, int* __restrict__ count, int n_nodes)
{
    __shared__ __align__(16) float tile[128][132];
    const int m = blockIdx.x;
    const float* W = (m == 0) ? w0 : (m == 1) ? w1 : (m == 2) ? w2
                   : (m == 3) ? w3 : (m == 4) ? w4 : w5;
    const int t = threadIdx.x;
    // zero histogram (spread across the 6 blocks)
    for (int idx = m * 256 + t; idx < n_nodes; idx += 6 * 256) count[idx] = 0;

    const float4* wg = (const float4*)W;
    #pragma unroll
    for (int it = 0; it < 16; ++it) {
        int f4 = t + it * 256;
        int k = f4 >> 5, c4 = f4 & 31;
        *((float4*)&tile[k][c4 * 4]) = wg[f4];
    }
    __syncthreads();
    ushort* oh = wth + m * 16384;
    #pragma unroll
    for (int it = 0; it < 64; ++it) {
        int idx = t + it * 256;
        int c = idx >> 7, k = idx & 127;
        oh[idx] = f2bf(tile[k][c]);
    }
}

// ---------------- qkv: persistent bf16 W in LDS; 64-row tiles, 16 rows/wave -
// grid (Gx, 3): blockIdx.y = matrix.

__global__ __launch_bounds__(256) void gemm_qkv_kernel(
    const float* __restrict__ x,
    const ushort* __restrict__ wth,
    const float* __restrict__ bq, const float* __restrict__ bk,
    const float* __restrict__ bv,
    float* __restrict__ q, ushort* __restrict__ k16, ushort* __restrict__ v16,
    int n_rows)
{
    __shared__ __align__(16) ushort wh[16384];
    const int t = threadIdx.x;
    const int w = t >> 6, l = t & 63;
    const int l15 = l & 15, l4 = l >> 4;
    const int m = blockIdx.y;

    STAGE_W(wth + m * 16384, wh);

    const float* bias = (m == 0) ? bq : (m == 1) ? bk : bv;
    float bsv[8];
    #pragma unroll
    for (int n = 0; n < 8; ++n) bsv[n] = bias[n * 16 + l15];
    __syncthreads();

    const int ntiles = (n_rows + 63) >> 6;
    for (int tile = blockIdx.x; tile < ntiles; tile += gridDim.x) {
        const int rowb = tile * 64 + w * 16;
        const size_t a0 = (size_t)(rowb + l15) * D + l4 * 8;
        bf16x8 ah[4], al[4];
        #pragma unroll
        for (int kk = 0; kk < 4; ++kk)
            load_split8(x + a0 + kk * 32, &ah[kk], &al[kk]);
        f32x4 acc[8];
        #pragma unroll
        for (int n = 0; n < 8; ++n) acc[n] = (f32x4){0.f, 0.f, 0.f, 0.f};
        TILE_MFMA16(ah, al, wh, acc);
        #pragma unroll
        for (int n = 0; n < 8; ++n) {
            int col = n * 16 + l15;
            #pragma unroll
            for (int r = 0; r < 4; ++r) {
                int row = rowb + l4 * 4 + r;
                if (row < n_rows) {
                    float val = acc[n][r] + bsv[n];
                    if (m == 0) q[(size_t)row * D + col] = val;
                    else if (m == 1) k16[(size_t)row * D + col] = f2bf(val);
                    else v16[(size_t)row * D + col] = f2bf(val);
                }
            }
        }
    }
}

// ---------------- CSR build ----------------

__global__ __launch_bounds__(256) void hist_kernel(
    const int* __restrict__ idx_i, int* __restrict__ count, int n_edges)
{
    int e = blockIdx.x * blockDim.x + threadIdx.x;
    if (e < n_edges) atomicAdd(&count[idx_i[e]], 1);
}

__global__ __launch_bounds__(256) void scan_reduce_kernel(
    const int* __restrict__ count, int* __restrict__ bsum, int n)
{
    __shared__ int wsum[4];
    const int t = threadIdx.x, lane = t & 63, w = t >> 6;
    int base = blockIdx.x * SCAN_CHUNK + t * 4;
    int s = 0;
    #pragma unroll
    for (int i = 0; i < 4; ++i) {
        int idx = base + i;
        if (idx < n) s += count[idx];
    }
    #pragma unroll
    for (int off = 1; off < 64; off <<= 1) s += __shfl_xor(s, off);
    if (lane == 0) wsum[w] = s;
    __syncthreads();
    if (t == 0) bsum[blockIdx.x] = wsum[0] + wsum[1] + wsum[2] + wsum[3];
}

// scan_write also derives its own block prefix from raw bsum (nb <= 64)

__global__ __launch_bounds__(256) void scan_write_kernel(
    const int* __restrict__ count, const int* __restrict__ bsum,
    int* __restrict__ row_start, int* __restrict__ cursor, int nb, int n)
{
    __shared__ int wtot[4];
    __shared__ int base_sh;
    const int t = threadIdx.x, lane = t & 63, w = t >> 6;
    if (w == 0) {   // wave 0: prefix of bsum over blocks < blockIdx.x (+ total)
        int v = (lane < nb) ? bsum[lane] : 0;
        int pre = (lane < (int)blockIdx.x) ? v : 0;
        #pragma unroll
        for (int off = 1; off < 64; off <<= 1) pre += __shfl_xor(pre, off);
        if (lane == 0) base_sh = pre;
        if (blockIdx.x == 0) {
            int tot = v;
            #pragma unroll
            for (int off = 1; off < 64; off <<= 1) tot += __shfl_xor(tot, off);
            if (lane == 0) row_start[n] = tot;
        }
    }
    int base = blockIdx.x * SCAN_CHUNK + t * 4;
    int c0 = 0, c1 = 0, c2 = 0, c3 = 0;
    if (base + 0 < n) c0 = count[base + 0];
    if (base + 1 < n) c1 = count[base + 1];
    if (base + 2 < n) c2 = count[base + 2];
    if (base + 3 < n) c3 = count[base + 3];
    int tsum = c0 + c1 + c2 + c3;
    int inc = tsum;
    #pragma unroll
    for (int off = 1; off < 64; off <<= 1) {
        int u = __shfl_up(inc, off);
        if (lane >= off) inc += u;
    }
    if (lane == 63) wtot[w] = inc;
    __syncthreads();
    int wb = 0;
    for (int i = 0; i < w; ++i) wb += wtot[i];
    int start = base_sh + wb + inc - tsum;
    if (base + 0 < n) { row_start[base + 0] = start;            cursor[base + 0] = start; }
    if (base + 1 < n) { row_start[base + 1] = start + c0;       cursor[base + 1] = start + c0; }
    if (base + 2 < n) { row_start[base + 2] = start + c0 + c1;  cursor[base + 2] = start + c0 + c1; }
    if (base + 3 < n) { row_start[base + 3] = start + c0 + c1 + c2; cursor[base + 3] = start + c0 + c1 + c2; }
}

__global__ __launch_bounds__(256) void scatter_kernel(
    const int* __restrict__ idx_i, const int* __restrict__ idx_j,
    int* __restrict__ cursor, int* __restrict__ ejs, int n_edges)
{
    int e = blockIdx.x * blockDim.x + threadIdx.x;
    if (e < n_edges) {
        int i = idx_i[e];
        int pos = atomicAdd(&cursor[i], 1);
        ejs[pos] = idx_j[e];
    }
}

// ---------------- fused per-node attention (bf16 K/V, defer-max) ------------

__global__ __launch_bounds__(256) void fused_agg_kernel(
    const float* __restrict__ q, const ushort* __restrict__ k16,
    const ushort* __restrict__ v16, const int* __restrict__ row_start,
    const int* __restrict__ ejs,
    ushort* __restrict__ aggh, ushort* __restrict__ aggl, int n_nodes)
{
    const int lane = threadIdx.x & 63;
    const int node = (blockIdx.x * blockDim.x + threadIdx.x) >> 6;
    if (node >= n_nodes) return;
    const int beg = row_start[node], end = row_start[node + 1];
    const int half = lane >> 5, sl = lane & 31;
    const int c4 = sl * 4;

    if (beg >= end) {   // empty segment: agg row = 0
        if (half == 0) {
            ((uint2*)(aggh + (size_t)node * D))[sl] = make_uint2(0u, 0u);
            ((uint2*)(aggl + (size_t)node * D))[sl] = make_uint2(0u, 0u);
        }
        return;
    }

    const float SC = 0.25f * 1.4426950408889634f;   // 1/sqrt(DH) * log2(e)
    float4 qv = *(const float4*)&q[(size_t)node * D + c4];
    qv.x *= SC; qv.y *= SC; qv.z *= SC; qv.w *= SC;
    float m = -INFINITY, l = 0.f;
    float a0 = 0.f, a1 = 0.f, a2 = 0.f, a3 = 0.f;

    int p = beg + half;
    uint2 kr0, vr0, kr1, vr1;
    if (p < end) {
        int j = ejs[p];
        kr0 = *(const uint2*)(k16 + (size_t)j * D + c4);
        vr0 = *(const uint2*)(v16 + (size_t)j * D + c4);
    }
    if (p + 2 < end) {
        int j = ejs[p + 2];
        kr1 = *(const uint2*)(k16 + (size_t)j * D + c4);
        vr1 = *(const uint2*)(v16 + (size_t)j * D + c4);
    }
    while (p < end) {
        uint2 kc = kr0, vc = vr0;
        kr0 = kr1; vr0 = vr1;
        if (p + 4 < end) {
            int j = ejs[p + 4];
            kr1 = *(const uint2*)(k16 + (size_t)j * D + c4);
            vr1 = *(const uint2*)(v16 + (size_t)j * D + c4);
        }
        float k0 = bf2f((ushort)kc.x), k1 = bf2f((ushort)(kc.x >> 16));
        float k2 = bf2f((ushort)kc.y), k3 = bf2f((ushort)(kc.y >> 16));
        float s = qv.x * k0 + qv.y * k1 + qv.z * k2 + qv.w * k3;
        s += __shfl_xor(s, 1);
        s += __shfl_xor(s, 2);
        float v0 = bf2f((ushort)vc.x), v1 = bf2f((ushort)(vc.x >> 16));
        float v2 = bf2f((ushort)vc.y), v3 = bf2f((ushort)(vc.y >> 16));
        if (__any(s > m + 8.f)) {
            float mn = fmaxf(m, s);
            float c  = exp2f(m - mn);      // exp2(-inf)=0 on first edge
            float pe = exp2f(s - mn);
            l  = l  * c + pe;
            a0 = a0 * c + pe * v0;
            a1 = a1 * c + pe * v1;
            a2 = a2 * c + pe * v2;
            a3 = a3 * c + pe * v3;
            m = mn;
        } else {
            float pe = exp2f(s - m);       // pe <= 2^8, terms referenced to m
            l += pe;
            a0 = fmaf(pe, v0, a0);
            a1 = fmaf(pe, v1, a1);
            a2 = fmaf(pe, v2, a2);
            a3 = fmaf(pe, v3, a3);
        }
        p += 2;
    }

    // merge halves
    float m2 = __shfl_xor(m, 32);
    float l2 = __shfl_xor(l, 32);
    float b0 = __shfl_xor(a0, 32);
    float b1 = __shfl_xor(a1, 32);
    float b2 = __shfl_xor(a2, 32);
    float b3 = __shfl_xor(a3, 32);
    float mm = fmaxf(m, m2);
    float cA = exp2f(m - mm);
    float cB = exp2f(m2 - mm);
    float L  = l * cA + l2 * cB;
    float A0 = a0 * cA + b0 * cB;
    float A1 = a1 * cA + b1 * cB;
    float A2 = a2 * cA + b2 * cB;
    float A3 = a3 * cA + b3 * cB;
    float invl = (L > 0.f) ? (1.0f / L) : 0.f;
    float o0 = A0 * invl, o1 = A1 * invl, o2 = A2 * invl, o3 = A3 * invl;

    ushort h0 = f2bf(o0), h1 = f2bf(o1), h2 = f2bf(o2), h3 = f2bf(o3);
    if (half == 0) {
        uint2 hv;
        hv.x = (unsigned int)h0 | ((unsigned int)h1 << 16);
        hv.y = (unsigned int)h2 | ((unsigned int)h3 << 16);
        ((uint2*)(aggh + (size_t)node * D))[sl] = hv;
    } else {
        ushort l0 = f2bf(o0 - bf2f(h0)), l1 = f2bf(o1 - bf2f(h1));
        ushort l2_ = f2bf(o2 - bf2f(h2)), l3 = f2bf(o3 - bf2f(h3));
        uint2 lv;
        lv.x = (unsigned int)l0 | ((unsigned int)l1 << 16);
        lv.y = (unsigned int)l2_ | ((unsigned int)l3 << 16);
        ((uint2*)(aggl + (size_t)node * D))[sl] = lv;
    }
}

// ---------------- oproj + LN1: persistent Wo; h = LN(x + agg@Wo + bo) -------

__global__ __launch_bounds__(256) void gemm_oproj_kernel(
    const ushort* __restrict__ aggh, const ushort* __restrict__ aggl,
    const float* __restrict__ x,
    const ushort* __restrict__ wth,
    const float* __restrict__ bo, const float* __restrict__ g1,
    const float* __restrict__ be1,
    ushort* __restrict__ hh, ushort* __restrict__ hl, int n_rows)
{
    __shared__ __align__(16) ushort wh[16384];
    const int t = threadIdx.x;
    const int w = t >> 6, l = t & 63;
    const int l15 = l & 15, l4 = l >> 4;

    STAGE_W(wth, wh);
    float bsv[8], gv[8], bev[8];
    #pragma unroll
    for (int n = 0; n < 8; ++n) {
        int col = n * 16 + l15;
        bsv[n] = bo[col]; gv[n] = g1[col]; bev[n] = be1[col];
    }
    __syncthreads();

    const int ntiles = (n_rows + 63) >> 6;
    for (int tile = blockIdx.x; tile < ntiles; tile += gridDim.x) {
        const int rowb = tile * 64 + w * 16;
        const size_t a0 = (size_t)(rowb + l15) * D + l4 * 8;
        bf16x8 ah[4], al[4];
        LOAD_A(aggh, aggl, a0, ah, al);
        f32x4 acc[8];
        #pragma unroll
        for (int n = 0; n < 8; ++n) acc[n] = (f32x4){0.f, 0.f, 0.f, 0.f};
        TILE_MFMA16(ah, al, wh, acc);
        float vals[8][4];
        #pragma unroll
        for (int n = 0; n < 8; ++n) {
            int col = n * 16 + l15;
            #pragma unroll
            for (int r = 0; r < 4; ++r) {
                int row = rowb + l4 * 4 + r;
                float xr = (row < n_rows) ? x[(size_t)row * D + col] : 0.f;
                vals[n][r] = acc[n][r] + bsv[n] + xr;
            }
        }
        #pragma unroll
        for (int r = 0; r < 4; ++r) {
            int row = rowb + l4 * 4 + r;
            float s = 0.f, ss = 0.f;
            #pragma unroll
            for (int n = 0; n < 8; ++n) { s += vals[n][r]; ss += vals[n][r] * vals[n][r]; }
            #pragma unroll
            for (int msk = 1; msk <= 8; msk <<= 1) {
                s += __shfl_xor(s, msk);
                ss += __shfl_xor(ss, msk);
            }
            float mean = s * (1.0f / D);
            float var = ss * (1.0f / D) - mean * mean;
            float inv = rsqrtf(var + 1e-5f);
            if (row < n_rows) {
                #pragma unroll
                for (int n = 0; n < 8; ++n) {
                    int col = n * 16 + l15;
                    float y = (vals[n][r] - mean) * inv * gv[n] + bev[n];
                    ushort hb = f2bf(y);
                    hh[(size_t)row * D + col] = hb;
                    hl[(size_t)row * D + col] = f2bf(y - bf2f(hb));
                }
            }
        }
    }
}

// ---------------- ffn1: t = relu(h@W1 + b1) -> th/tl (bf16 split) -----------

__global__ __launch_bounds__(256) void gemm_ffn1_kernel(
    const ushort* __restrict__ hh, const ushort* __restrict__ hl,
    const ushort* __restrict__ wth,
    const float* __restrict__ bb1,
    ushort* __restrict__ th, ushort* __restrict__ tl, int n_rows)
{
    __shared__ __align__(16) ushort wh[16384];
    const int t = threadIdx.x;
    const int w = t >> 6, l = t & 63;
    const int l15 = l & 15, l4 = l >> 4;

    STAGE_W(wth, wh);
    float bsv[8];
    #pragma unroll
    for (int n = 0; n < 8; ++n) bsv[n] = bb1[n * 16 + l15];
    __syncthreads();

    const int ntiles = (n_rows + 63) >> 6;
    for (int tile = blockIdx.x; tile < ntiles; tile += gridDim.x) {
        const int rowb = tile * 64 + w * 16;
        const size_t a0 = (size_t)(rowb + l15) * D + l4 * 8;
        bf16x8 ah[4], al[4];
        LOAD_A(hh, hl, a0, ah, al);
        f32x4 acc[8];
        #pragma unroll
        for (int n = 0; n < 8; ++n) acc[n] = (f32x4){0.f, 0.f, 0.f, 0.f};
        TILE_MFMA16(ah, al, wh, acc);
        #pragma unroll
        for (int n = 0; n < 8; ++n) {
            int col = n * 16 + l15;
            #pragma unroll
            for (int r = 0; r < 4; ++r) {
                int row = rowb + l4 * 4 + r;
                if (row < n_rows) {
                    float tv = fmaxf(acc[n][r] + bsv[n], 0.f);
                    ushort hb = f2bf(tv);
                    th[(size_t)row * D + col] = hb;
                    tl[(size_t)row * D + col] = f2bf(tv - bf2f(hb));
                }
            }
        }
    }
}

// ---------------- ffn2: out = LN(h + t@W2 + b2) -----------------------------

__global__ __launch_bounds__(256) void gemm_ffn2_kernel(
    const ushort* __restrict__ th, const ushort* __restrict__ tl,
    const ushort* __restrict__ hh, const ushort* __restrict__ hl,
    const ushort* __restrict__ wth,
    const float* __restrict__ bb2, const float* __restrict__ g2,
    const float* __restrict__ be2,
    float* __restrict__ out, int n_rows)
{
    __shared__ __align__(16) ushort wh[16384];
    const int t = threadIdx.x;
    const int w = t >> 6, l = t & 63;
    const int l15 = l & 15, l4 = l >> 4;

    STAGE_W(wth, wh);
    float bsv[8], gv[8], bev[8];
    #pragma unroll
    for (int n = 0; n < 8; ++n) {
        int col = n * 16 + l15;
        bsv[n] = bb2[col]; gv[n] = g2[col]; bev[n] = be2[col];
    }
    __syncthreads();

    const int ntiles = (n_rows + 63) >> 6;
    for (int tile = blockIdx.x; tile < ntiles; tile += gridDim.x) {
        const int rowb = tile * 64 + w * 16;
        const size_t a0 = (size_t)(rowb + l15) * D + l4 * 8;
        bf16x8 ah[4], al[4];
        LOAD_A(th, tl, a0, ah, al);
        f32x4 acc[8];
        #pragma unroll
        for (int n = 0; n < 8; ++n) acc[n] = (f32x4){0.f, 0.f, 0.f, 0.f};
        TILE_MFMA16(ah, al, wh, acc);
        float vals[8][4];
        #pragma unroll
        for (int n = 0; n < 8; ++n) {
            int col = n * 16 + l15;
            #pragma unroll
            for (int r = 0; r < 4; ++r) {
                int row = rowb + l4 * 4 + r;
                float hr = 0.f;
                if (row < n_rows)
                    hr = bf2f(hh[(size_t)row * D + col]) + bf2f(hl[(size_t)row * D + col]);
                vals[n][r] = acc[n][r] + bsv[n] + hr;
            }
        }
        #pragma unroll
        for (int r = 0; r < 4; ++r) {
            int row = rowb + l4 * 4 + r;
            float s = 0.f, ss = 0.f;
            #pragma unroll
            for (int n = 0; n < 8; ++n) { s += vals[n][r]; ss += vals[n][r] * vals[n][r]; }
            #pragma unroll
            for (int msk = 1; msk <= 8; msk <<= 1) {
                s += __shfl_xor(s, msk);
                ss += __shfl_xor(ss, msk);
            }
            float mean = s * (1.0f / D);
            float var = ss * (1.0f / D) - mean * mean;
            float inv = rsqrtf(var + 1e-5f);
            if (row < n_rows) {
                #pragma unroll
                for (int n = 0; n < 8; ++n) {
                    int col = n * 16 + l15;
                    out[(size_t)row * D + col] = (vals[n][r] - mean) * inv * gv[n] + bev[n];
                }
            }
        }
    }
}

// ---------------- launch ----------------

extern "C" void kernel_launch(void* const* d_in, const int* in_sizes, int n_in,
                              void* d_out, int out_size, void* d_ws, size_t ws_size,
                              hipStream_t stream) {
    const float* x     = (const float*)d_in[0];
    const int*   idx_i = (const int*)d_in[1];
    const int*   idx_j = (const int*)d_in[2];
    const float* Wq = (const float*)d_in[3];
    const float* bq = (const float*)d_in[4];
    const float* Wk = (const float*)d_in[5];
    const float* bk = (const float*)d_in[6];
    const float* Wv = (const float*)d_in[7];
    const float* bv = (const float*)d_in[8];
    const float* Wo = (const float*)d_in[9];
    const float* bo = (const float*)d_in[10];
    const float* g1 = (const float*)d_in[11];
    const float* be1 = (const float*)d_in[12];
    const float* W1 = (const float*)d_in[13];
    const float* bb1 = (const float*)d_in[14];
    const float* W2 = (const float*)d_in[15];
    const float* bb2 = (const float*)d_in[16];
    const float* g2 = (const float*)d_in[17];
    const float* be2 = (const float*)d_in[18];

    const int N_ = in_sizes[0] / D;
    const int E_ = in_sizes[1];
    const size_t ND = (size_t)N_ * D;
    const int nb = (N_ + SCAN_CHUNK - 1) / SCAN_CHUNK;   // 49 for N=50000 (<=64 required)

    float* ws = (float*)d_ws;
    float* q = ws;                         // ND f32 (later reused as hh/hl bf16 split)
    ushort* k16 = (ushort*)(q + ND);       // ND bf16 (later reused as th)
    ushort* v16 = k16 + ND;                // ND bf16 (later reused as tl)
    int* count     = (int*)(v16 + ND);     // N
    int* row_start = count + N_;           // N+1
    int* cursor    = row_start + N_ + 1;   // N
    int* bsum      = cursor + N_;          // 64
    int* ejs       = bsum + 64;            // E
    ushort* aggh = (ushort*)(ejs + E_);    // ND bf16
    ushort* aggl = aggh + ND;              // ND bf16
    ushort* wth = aggl + ND;               // 6*128*128 bf16
    ushort* hh = (ushort*)q;
    ushort* hl = hh + ND;
    ushort* th = k16;                      // k16/v16 dead after fused_agg
    ushort* tl = v16;

    prep_w_kernel<<<6, 256, 0, stream>>>(Wq, Wk, Wv, Wo, W1, W2, wth, count, N_);
    {
        dim3 g(391, 3);   // 782 tiles per matrix, 2 tiles/block
        gemm_qkv_kernel<<<g, 256, 0, stream>>>(x, wth, bq, bk, bv,
                                               q, k16, v16, N_);
    }
    hist_kernel<<<(E_ + 255) / 256, 256, 0, stream>>>(idx_i, count, E_);
    scan_reduce_kernel<<<nb, 256, 0, stream>>>(count, bsum, N_);
    scan_write_kernel<<<nb, 256, 0, stream>>>(count, bsum, row_start, cursor, nb, N_);
    scatter_kernel<<<(E_ + 255) / 256, 256, 0, stream>>>(idx_i, idx_j, cursor, ejs, E_);
    fused_agg_kernel<<<(N_ + 3) / 4, 256, 0, stream>>>(q, k16, v16, row_start, ejs,
                                                       aggh, aggl, N_);
    gemm_oproj_kernel<<<391, 256, 0, stream>>>(aggh, aggl, x, wth + 3 * 16384,
                                               bo, g1, be1, hh, hl, N_);
    gemm_ffn1_kernel<<<391, 256, 0, stream>>>(hh, hl, wth + 4 * 16384,
                                              bb1, th, tl, N_);
    gemm_ffn2_kernel<<<391, 256, 0, stream>>>(th, tl, hh, hl, wth + 5 * 16384,
                                              bb2, g2, be2, (float*)d_out, N_);
}

// Round 18
// 252.730 us; speedup vs baseline: 1.0849x; 1.0849x over previous
//
#include <hip/hip_runtime.h>
#include <hip/hip_bf16.h>
#include <math.h>

#define D 128
#define H 8
#define DH 16
#define SCAN_CHUNK 1024

typedef __attribute__((ext_vector_type(8))) short bf16x8;
typedef __attribute__((ext_vector_type(4))) float f32x4;

__device__ __forceinline__ float bf2f(ushort u) {
    unsigned int x = ((unsigned int)u) << 16;
    float f;
    __builtin_memcpy(&f, &x, 4);
    return f;
}
__device__ __forceinline__ ushort f2bf(float f) {
    __hip_bfloat16 h = __float2bfloat16(f);
    ushort u;
    __builtin_memcpy(&u, &h, 2);
    return u;
}

// load 8 consecutive f32 and split into bf16 hi/lo fragments in-register
__device__ __forceinline__ void load_split8(const float* src, bf16x8* hi, bf16x8* lo) {
    float4 a = *(const float4*)src;
    float4 b = *(const float4*)(src + 4);
    float xs[8] = {a.x, a.y, a.z, a.w, b.x, b.y, b.z, b.w};
    short hv[8], lv[8];
    #pragma unroll
    for (int i = 0; i < 8; ++i) {
        ushort hb = f2bf(xs[i]);
        hv[i] = (short)hb;
        lv[i] = (short)f2bf(xs[i] - bf2f(hb));
    }
    *hi = (bf16x8){hv[0], hv[1], hv[2], hv[3], hv[4], hv[5], hv[6], hv[7]};
    *lo = (bf16x8){lv[0], lv[1], lv[2], lv[3], lv[4], lv[5], lv[6], lv[7]};
}

// Stage a 128x128 bf16 matrix (32KB) global -> LDS, XOR-swizzled 16B slots.
// 256-thread version: 2048 slots, 8 per thread.
#define STAGE_W(SRC, LDSBUF)                                              \
    {                                                                      \
        _Pragma("unroll")                                                  \
        for (int it_ = 0; it_ < 8; ++it_) {                                \
            int idx16_ = t + it_ * 256;                                    \
            int row_ = idx16_ >> 4, c16_ = idx16_ & 15;                    \
            int d_ = (row_ << 7) + ((c16_ ^ (row_ & 7)) << 3);             \
            *(bf16x8*)((LDSBUF) + d_) = *(const bf16x8*)((SRC) + idx16_ * 8); \
        }                                                                  \
    }

#define LOAD_A(SRCH, SRCL, BASE, AH, AL)                                   \
    _Pragma("unroll")                                                      \
    for (int kk_ = 0; kk_ < 4; ++kk_) {                                    \
        AH[kk_] = *(const bf16x8*)((SRCH) + (BASE) + kk_ * 32);            \
        AL[kk_] = *(const bf16x8*)((SRCL) + (BASE) + kk_ * 32);            \
    }

// 32-rows-per-wave MFMA tile, bf16 weights (2-term split: (Ah+Al)*Bh)
#define TILE_MFMA(AH0, AL0, AH1, AL1, WH, ACC0, ACC1)                      \
    _Pragma("unroll")                                                      \
    for (int kk = 0; kk < 4; ++kk) {                                       \
        _Pragma("unroll")                                                  \
        for (int n = 0; n < 8; ++n) {                                      \
            int rn = n * 16 + l15;                                         \
            int off = (rn << 7) + (((l4 + kk * 4) ^ (rn & 7)) << 3);       \
            bf16x8 bh = *(const bf16x8*)((WH) + off);                      \
            ACC0[n] = __builtin_amdgcn_mfma_f32_16x16x32_bf16(AH0[kk], bh, ACC0[n], 0, 0, 0); \
            ACC0[n] = __builtin_amdgcn_mfma_f32_16x16x32_bf16(AL0[kk], bh, ACC0[n], 0, 0, 0); \
            ACC1[n] = __builtin_amdgcn_mfma_f32_16x16x32_bf16(AH1[kk], bh, ACC1[n], 0, 0, 0); \
            ACC1[n] = __builtin_amdgcn_mfma_f32_16x16x32_bf16(AL1[kk], bh, ACC1[n], 0, 0, 0); \
        }                                                                  \
    }

// ---------------- prep_w: transpose 6 weight matrices (bf16) + zero count ---

__global__ __launch_bounds__(256) void prep_w_kernel(
    const float* __restrict__ w0, const float* __restrict__ w1,
    const float* __restrict__ w2, const float* __restrict__ w3,
    const float* __restrict__ w4, const float* __restrict__ w5,
    ushort* __restrict__ wth, int* __restrict__ count, int n_nodes)
{
    __shared__ __align__(16) float tile[128][132];
    const int m = blockIdx.x;
    const float* W = (m == 0) ? w0 : (m == 1) ? w1 : (m == 2) ? w2
                   : (m == 3) ? w3 : (m == 4) ? w4 : w5;
    const int t = threadIdx.x;
    // zero histogram (spread across the 6 blocks)
    for (int idx = m * 256 + t; idx < n_nodes; idx += 6 * 256) count[idx] = 0;

    const float4* wg = (const float4*)W;
    #pragma unroll
    for (int it = 0; it < 16; ++it) {
        int f4 = t + it * 256;
        int k = f4 >> 5, c4 = f4 & 31;
        *((float4*)&tile[k][c4 * 4]) = wg[f4];
    }
    __syncthreads();
    ushort* oh = wth + m * 16384;
    #pragma unroll
    for (int it = 0; it < 64; ++it) {
        int idx = t + it * 256;
        int c = idx >> 7, k = idx & 127;
        oh[idx] = f2bf(tile[k][c]);
    }
}

// ---------------- qkv: persistent bf16 W in LDS; 128-row tiles, 32 rows/wave
// grid (Gx, 3): blockIdx.y = matrix. blockIdx.y==0 blocks also run the edge
// histogram (hides atomics under the latency-bound tile loop).

__global__ __launch_bounds__(256) void gemm_qkv_kernel(
    const float* __restrict__ x,
    const ushort* __restrict__ wth,
    const float* __restrict__ bq, const float* __restrict__ bk,
    const float* __restrict__ bv,
    const int* __restrict__ idx_i, int* __restrict__ count, int n_edges,
    float* __restrict__ q, ushort* __restrict__ k16, ushort* __restrict__ v16,
    int n_rows)
{
    __shared__ __align__(16) ushort wh[16384];
    const int t = threadIdx.x;
    const int w = t >> 6, l = t & 63;
    const int l15 = l & 15, l4 = l >> 4;
    const int m = blockIdx.y;

    STAGE_W(wth + m * 16384, wh);

    // fused histogram: matrix-0 blocks cover all edges (overlaps tile loop)
    if (m == 0) {
        const int stride = gridDim.x * 256;
        for (int e = blockIdx.x * 256 + t; e < n_edges; e += stride)
            atomicAdd(&count[idx_i[e]], 1);
    }

    const float* bias = (m == 0) ? bq : (m == 1) ? bk : bv;
    float bsv[8];
    #pragma unroll
    for (int n = 0; n < 8; ++n) bsv[n] = bias[n * 16 + l15];
    __syncthreads();

    const int ntiles = (n_rows + 127) >> 7;
    for (int tile = blockIdx.x; tile < ntiles; tile += gridDim.x) {
        const int rowb = tile * 128 + w * 32;
        const size_t a0 = (size_t)(rowb + l15) * D + l4 * 8;
        bf16x8 ah0[4], al0[4], ah1[4], al1[4];
        #pragma unroll
        for (int kk = 0; kk < 4; ++kk) {
            load_split8(x + a0 + kk * 32, &ah0[kk], &al0[kk]);
            load_split8(x + a0 + 16 * D + kk * 32, &ah1[kk], &al1[kk]);
        }
        f32x4 acc0[8], acc1[8];
        #pragma unroll
        for (int n = 0; n < 8; ++n) {
            acc0[n] = (f32x4){0.f, 0.f, 0.f, 0.f};
            acc1[n] = (f32x4){0.f, 0.f, 0.f, 0.f};
        }
        TILE_MFMA(ah0, al0, ah1, al1, wh, acc0, acc1);
        #pragma unroll
        for (int n = 0; n < 8; ++n) {
            int col = n * 16 + l15;
            #pragma unroll
            for (int r = 0; r < 4; ++r) {
                int row0 = rowb + l4 * 4 + r;
                int row1 = row0 + 16;
                if (row0 < n_rows) {
                    float val = acc0[n][r] + bsv[n];
                    if (m == 0) q[(size_t)row0 * D + col] = val;
                    else if (m == 1) k16[(size_t)row0 * D + col] = f2bf(val);
                    else v16[(size_t)row0 * D + col] = f2bf(val);
                }
                if (row1 < n_rows) {
                    float val = acc1[n][r] + bsv[n];
                    if (m == 0) q[(size_t)row1 * D + col] = val;
                    else if (m == 1) k16[(size_t)row1 * D + col] = f2bf(val);
                    else v16[(size_t)row1 * D + col] = f2bf(val);
                }
            }
        }
    }
}

// ---------------- CSR build ----------------

__global__ __launch_bounds__(256) void scan_reduce_kernel(
    const int* __restrict__ count, int* __restrict__ bsum, int n)
{
    __shared__ int wsum[4];
    const int t = threadIdx.x, lane = t & 63, w = t >> 6;
    int base = blockIdx.x * SCAN_CHUNK + t * 4;
    int s = 0;
    #pragma unroll
    for (int i = 0; i < 4; ++i) {
        int idx = base + i;
        if (idx < n) s += count[idx];
    }
    #pragma unroll
    for (int off = 1; off < 64; off <<= 1) s += __shfl_xor(s, off);
    if (lane == 0) wsum[w] = s;
    __syncthreads();
    if (t == 0) bsum[blockIdx.x] = wsum[0] + wsum[1] + wsum[2] + wsum[3];
}

// scan_write derives its own block prefix from raw bsum (nb <= 64)

__global__ __launch_bounds__(256) void scan_write_kernel(
    const int* __restrict__ count, const int* __restrict__ bsum,
    int* __restrict__ row_start, int* __restrict__ cursor, int nb, int n)
{
    __shared__ int wtot[4];
    __shared__ int base_sh;
    const int t = threadIdx.x, lane = t & 63, w = t >> 6;
    if (w == 0) {   // wave 0: prefix of bsum over blocks < blockIdx.x (+ total)
        int v = (lane < nb) ? bsum[lane] : 0;
        int pre = (lane < (int)blockIdx.x) ? v : 0;
        #pragma unroll
        for (int off = 1; off < 64; off <<= 1) pre += __shfl_xor(pre, off);
        if (lane == 0) base_sh = pre;
        if (blockIdx.x == 0) {
            int tot = v;
            #pragma unroll
            for (int off = 1; off < 64; off <<= 1) tot += __shfl_xor(tot, off);
            if (lane == 0) row_start[n] = tot;
        }
    }
    int base = blockIdx.x * SCAN_CHUNK + t * 4;
    int c0 = 0, c1 = 0, c2 = 0, c3 = 0;
    if (base + 0 < n) c0 = count[base + 0];
    if (base + 1 < n) c1 = count[base + 1];
    if (base + 2 < n) c2 = count[base + 2];
    if (base + 3 < n) c3 = count[base + 3];
    int tsum = c0 + c1 + c2 + c3;
    int inc = tsum;
    #pragma unroll
    for (int off = 1; off < 64; off <<= 1) {
        int u = __shfl_up(inc, off);
        if (lane >= off) inc += u;
    }
    if (lane == 63) wtot[w] = inc;
    __syncthreads();
    int wb = 0;
    for (int i = 0; i < w; ++i) wb += wtot[i];
    int start = base_sh + wb + inc - tsum;
    if (base + 0 < n) { row_start[base + 0] = start;            cursor[base + 0] = start; }
    if (base + 1 < n) { row_start[base + 1] = start + c0;       cursor[base + 1] = start + c0; }
    if (base + 2 < n) { row_start[base + 2] = start + c0 + c1;  cursor[base + 2] = start + c0 + c1; }
    if (base + 3 < n) { row_start[base + 3] = start + c0 + c1 + c2; cursor[base + 3] = start + c0 + c1 + c2; }
}

__global__ __launch_bounds__(256) void scatter_kernel(
    const int* __restrict__ idx_i, const int* __restrict__ idx_j,
    int* __restrict__ cursor, int* __restrict__ ejs, int n_edges)
{
    int e = blockIdx.x * blockDim.x + threadIdx.x;
    if (e < n_edges) {
        int i = idx_i[e];
        int pos = atomicAdd(&cursor[i], 1);
        ejs[pos] = idx_j[e];
    }
}

// ---------------- fused per-node attention (bf16 K/V, defer-max) ------------

__global__ __launch_bounds__(256) void fused_agg_kernel(
    const float* __restrict__ q, const ushort* __restrict__ k16,
    const ushort* __restrict__ v16, const int* __restrict__ row_start,
    const int* __restrict__ ejs,
    ushort* __restrict__ aggh, ushort* __restrict__ aggl, int n_nodes)
{
    const int lane = threadIdx.x & 63;
    const int node = (blockIdx.x * blockDim.x + threadIdx.x) >> 6;
    if (node >= n_nodes) return;
    const int beg = row_start[node], end = row_start[node + 1];
    const int half = lane >> 5, sl = lane & 31;
    const int c4 = sl * 4;

    if (beg >= end) {   // empty segment: agg row = 0
        if (half == 0) {
            ((uint2*)(aggh + (size_t)node * D))[sl] = make_uint2(0u, 0u);
            ((uint2*)(aggl + (size_t)node * D))[sl] = make_uint2(0u, 0u);
        }
        return;
    }

    const float SC = 0.25f * 1.4426950408889634f;   // 1/sqrt(DH) * log2(e)
    float4 qv = *(const float4*)&q[(size_t)node * D + c4];
    qv.x *= SC; qv.y *= SC; qv.z *= SC; qv.w *= SC;
    float m = -INFINITY, l = 0.f;
    float a0 = 0.f, a1 = 0.f, a2 = 0.f, a3 = 0.f;

    int p = beg + half;
    uint2 kr0, vr0, kr1, vr1;
    if (p < end) {
        int j = ejs[p];
        kr0 = *(const uint2*)(k16 + (size_t)j * D + c4);
        vr0 = *(const uint2*)(v16 + (size_t)j * D + c4);
    }
    if (p + 2 < end) {
        int j = ejs[p + 2];
        kr1 = *(const uint2*)(k16 + (size_t)j * D + c4);
        vr1 = *(const uint2*)(v16 + (size_t)j * D + c4);
    }
    while (p < end) {
        uint2 kc = kr0, vc = vr0;
        kr0 = kr1; vr0 = vr1;
        if (p + 4 < end) {
            int j = ejs[p + 4];
            kr1 = *(const uint2*)(k16 + (size_t)j * D + c4);
            vr1 = *(const uint2*)(v16 + (size_t)j * D + c4);
        }
        float k0 = bf2f((ushort)kc.x), k1 = bf2f((ushort)(kc.x >> 16));
        float k2 = bf2f((ushort)kc.y), k3 = bf2f((ushort)(kc.y >> 16));
        float s = qv.x * k0 + qv.y * k1 + qv.z * k2 + qv.w * k3;
        s += __shfl_xor(s, 1);
        s += __shfl_xor(s, 2);
        float v0 = bf2f((ushort)vc.x), v1 = bf2f((ushort)(vc.x >> 16));
        float v2 = bf2f((ushort)vc.y), v3 = bf2f((ushort)(vc.y >> 16));
        if (__any(s > m + 8.f)) {
            float mn = fmaxf(m, s);
            float c  = exp2f(m - mn);      // exp2(-inf)=0 on first edge
            float pe = exp2f(s - mn);
            l  = l  * c + pe;
            a0 = a0 * c + pe * v0;
            a1 = a1 * c + pe * v1;
            a2 = a2 * c + pe * v2;
            a3 = a3 * c + pe * v3;
            m = mn;
        } else {
            float pe = exp2f(s - m);       // pe <= 2^8, terms referenced to m
            l += pe;
            a0 = fmaf(pe, v0, a0);
            a1 = fmaf(pe, v1, a1);
            a2 = fmaf(pe, v2, a2);
            a3 = fmaf(pe, v3, a3);
        }
        p += 2;
    }

    // merge halves
    float m2 = __shfl_xor(m, 32);
    float l2 = __shfl_xor(l, 32);
    float b0 = __shfl_xor(a0, 32);
    float b1 = __shfl_xor(a1, 32);
    float b2 = __shfl_xor(a2, 32);
    float b3 = __shfl_xor(a3, 32);
    float mm = fmaxf(m, m2);
    float cA = exp2f(m - mm);
    float cB = exp2f(m2 - mm);
    float L  = l * cA + l2 * cB;
    float A0 = a0 * cA + b0 * cB;
    float A1 = a1 * cA + b1 * cB;
    float A2 = a2 * cA + b2 * cB;
    float A3 = a3 * cA + b3 * cB;
    float invl = (L > 0.f) ? (1.0f / L) : 0.f;
    float o0 = A0 * invl, o1 = A1 * invl, o2 = A2 * invl, o3 = A3 * invl;

    ushort h0 = f2bf(o0), h1 = f2bf(o1), h2 = f2bf(o2), h3 = f2bf(o3);
    if (half == 0) {
        uint2 hv;
        hv.x = (unsigned int)h0 | ((unsigned int)h1 << 16);
        hv.y = (unsigned int)h2 | ((unsigned int)h3 << 16);
        ((uint2*)(aggh + (size_t)node * D))[sl] = hv;
    } else {
        ushort l0 = f2bf(o0 - bf2f(h0)), l1 = f2bf(o1 - bf2f(h1));
        ushort l2_ = f2bf(o2 - bf2f(h2)), l3 = f2bf(o3 - bf2f(h3));
        uint2 lv;
        lv.x = (unsigned int)l0 | ((unsigned int)l1 << 16);
        lv.y = (unsigned int)l2_ | ((unsigned int)l3 << 16);
        ((uint2*)(aggl + (size_t)node * D))[sl] = lv;
    }
}

// ---------------- oproj + LN1: persistent Wo; h = LN(x + agg@Wo + bo) -------

__global__ __launch_bounds__(256) void gemm_oproj_kernel(
    const ushort* __restrict__ aggh, const ushort* __restrict__ aggl,
    const float* __restrict__ x,
    const ushort* __restrict__ wth,
    const float* __restrict__ bo, const float* __restrict__ g1,
    const float* __restrict__ be1,
    ushort* __restrict__ hh, ushort* __restrict__ hl, int n_rows)
{
    __shared__ __align__(16) ushort wh[16384];
    const int t = threadIdx.x;
    const int w = t >> 6, l = t & 63;
    const int l15 = l & 15, l4 = l >> 4;

    STAGE_W(wth, wh);
    float bsv[8], gv[8], bev[8];
    #pragma unroll
    for (int n = 0; n < 8; ++n) {
        int col = n * 16 + l15;
        bsv[n] = bo[col]; gv[n] = g1[col]; bev[n] = be1[col];
    }
    __syncthreads();

    const int ntiles = (n_rows + 127) >> 7;
    for (int tile = blockIdx.x; tile < ntiles; tile += gridDim.x) {
        const int rowb = tile * 128 + w * 32;
        const size_t a0 = (size_t)(rowb + l15) * D + l4 * 8;
        bf16x8 ah0[4], al0[4], ah1[4], al1[4];
        LOAD_A(aggh, aggl, a0, ah0, al0);
        LOAD_A(aggh, aggl, a0 + 16 * D, ah1, al1);
        f32x4 acc0[8], acc1[8];
        #pragma unroll
        for (int n = 0; n < 8; ++n) {
            acc0[n] = (f32x4){0.f, 0.f, 0.f, 0.f};
            acc1[n] = (f32x4){0.f, 0.f, 0.f, 0.f};
        }
        TILE_MFMA(ah0, al0, ah1, al1, wh, acc0, acc1);
        // epilogue for both row groups
        #pragma unroll
        for (int g = 0; g < 2; ++g) {
            f32x4* acc = g ? acc1 : acc0;
            int rbase = rowb + g * 16;
            float vals[8][4];
            #pragma unroll
            for (int n = 0; n < 8; ++n) {
                int col = n * 16 + l15;
                #pragma unroll
                for (int r = 0; r < 4; ++r) {
                    int row = rbase + l4 * 4 + r;
                    float xr = (row < n_rows) ? x[(size_t)row * D + col] : 0.f;
                    vals[n][r] = acc[n][r] + bsv[n] + xr;
                }
            }
            #pragma unroll
            for (int r = 0; r < 4; ++r) {
                int row = rbase + l4 * 4 + r;
                float s = 0.f, ss = 0.f;
                #pragma unroll
                for (int n = 0; n < 8; ++n) { s += vals[n][r]; ss += vals[n][r] * vals[n][r]; }
                #pragma unroll
                for (int msk = 1; msk <= 8; msk <<= 1) {
                    s += __shfl_xor(s, msk);
                    ss += __shfl_xor(ss, msk);
                }
                float mean = s * (1.0f / D);
                float var = ss * (1.0f / D) - mean * mean;
                float inv = rsqrtf(var + 1e-5f);
                if (row < n_rows) {
                    #pragma unroll
                    for (int n = 0; n < 8; ++n) {
                        int col = n * 16 + l15;
                        float y = (vals[n][r] - mean) * inv * gv[n] + bev[n];
                        ushort hb = f2bf(y);
                        hh[(size_t)row * D + col] = hb;
                        hl[(size_t)row * D + col] = f2bf(y - bf2f(hb));
                    }
                }
            }
        }
    }
}

// ---------------- ffn1: t = relu(h@W1 + b1) -> th/tl (bf16 split) -----------

__global__ __launch_bounds__(256) void gemm_ffn1_kernel(
    const ushort* __restrict__ hh, const ushort* __restrict__ hl,
    const ushort* __restrict__ wth,
    const float* __restrict__ bb1,
    ushort* __restrict__ th, ushort* __restrict__ tl, int n_rows)
{
    __shared__ __align__(16) ushort wh[16384];
    const int t = threadIdx.x;
    const int w = t >> 6, l = t & 63;
    const int l15 = l & 15, l4 = l >> 4;

    STAGE_W(wth, wh);
    float bsv[8];
    #pragma unroll
    for (int n = 0; n < 8; ++n) bsv[n] = bb1[n * 16 + l15];
    __syncthreads();

    const int ntiles = (n_rows + 127) >> 7;
    for (int tile = blockIdx.x; tile < ntiles; tile += gridDim.x) {
        const int rowb = tile * 128 + w * 32;
        const size_t a0 = (size_t)(rowb + l15) * D + l4 * 8;
        bf16x8 ah0[4], al0[4], ah1[4], al1[4];
        LOAD_A(hh, hl, a0, ah0, al0);
        LOAD_A(hh, hl, a0 + 16 * D, ah1, al1);
        f32x4 acc0[8], acc1[8];
        #pragma unroll
        for (int n = 0; n < 8; ++n) {
            acc0[n] = (f32x4){0.f, 0.f, 0.f, 0.f};
            acc1[n] = (f32x4){0.f, 0.f, 0.f, 0.f};
        }
        TILE_MFMA(ah0, al0, ah1, al1, wh, acc0, acc1);
        #pragma unroll
        for (int n = 0; n < 8; ++n) {
            int col = n * 16 + l15;
            #pragma unroll
            for (int r = 0; r < 4; ++r) {
                int row0 = rowb + l4 * 4 + r;
                int row1 = row0 + 16;
                if (row0 < n_rows) {
                    float tv = fmaxf(acc0[n][r] + bsv[n], 0.f);
                    ushort hb = f2bf(tv);
                    th[(size_t)row0 * D + col] = hb;
                    tl[(size_t)row0 * D + col] = f2bf(tv - bf2f(hb));
                }
                if (row1 < n_rows) {
                    float tv = fmaxf(acc1[n][r] + bsv[n], 0.f);
                    ushort hb = f2bf(tv);
                    th[(size_t)row1 * D + col] = hb;
                    tl[(size_t)row1 * D + col] = f2bf(tv - bf2f(hb));
                }
            }
        }
    }
}

// ---------------- ffn2: out = LN(h + t@W2 + b2) -----------------------------

__global__ __launch_bounds__(256) void gemm_ffn2_kernel(
    const ushort* __restrict__ th, const ushort* __restrict__ tl,
    const ushort* __restrict__ hh, const ushort* __restrict__ hl,
    const ushort* __restrict__ wth,
    const float* __restrict__ bb2, const float* __restrict__ g2,
    const float* __restrict__ be2,
    float* __restrict__ out, int n_rows)
{
    __shared__ __align__(16) ushort wh[16384];
    const int t = threadIdx.x;
    const int w = t >> 6, l = t & 63;
    const int l15 = l & 15, l4 = l >> 4;

    STAGE_W(wth, wh);
    float bsv[8], gv[8], bev[8];
    #pragma unroll
    for (int n = 0; n < 8; ++n) {
        int col = n * 16 + l15;
        bsv[n] = bb2[col]; gv[n] = g2[col]; bev[n] = be2[col];
    }
    __syncthreads();

    const int ntiles = (n_rows + 127) >> 7;
    for (int tile = blockIdx.x; tile < ntiles; tile += gridDim.x) {
        const int rowb = tile * 128 + w * 32;
        const size_t a0 = (size_t)(rowb + l15) * D + l4 * 8;
        bf16x8 ah0[4], al0[4], ah1[4], al1[4];
        LOAD_A(th, tl, a0, ah0, al0);
        LOAD_A(th, tl, a0 + 16 * D, ah1, al1);
        f32x4 acc0[8], acc1[8];
        #pragma unroll
        for (int n = 0; n < 8; ++n) {
            acc0[n] = (f32x4){0.f, 0.f, 0.f, 0.f};
            acc1[n] = (f32x4){0.f, 0.f, 0.f, 0.f};
        }
        TILE_MFMA(ah0, al0, ah1, al1, wh, acc0, acc1);
        #pragma unroll
        for (int g = 0; g < 2; ++g) {
            f32x4* acc = g ? acc1 : acc0;
            int rbase = rowb + g * 16;
            float vals[8][4];
            #pragma unroll
            for (int n = 0; n < 8; ++n) {
                int col = n * 16 + l15;
                #pragma unroll
                for (int r = 0; r < 4; ++r) {
                    int row = rbase + l4 * 4 + r;
                    float hr = 0.f;
                    if (row < n_rows)
                        hr = bf2f(hh[(size_t)row * D + col]) + bf2f(hl[(size_t)row * D + col]);
                    vals[n][r] = acc[n][r] + bsv[n] + hr;
                }
            }
            #pragma unroll
            for (int r = 0; r < 4; ++r) {
                int row = rbase + l4 * 4 + r;
                float s = 0.f, ss = 0.f;
                #pragma unroll
                for (int n = 0; n < 8; ++n) { s += vals[n][r]; ss += vals[n][r] * vals[n][r]; }
                #pragma unroll
                for (int msk = 1; msk <= 8; msk <<= 1) {
                    s += __shfl_xor(s, msk);
                    ss += __shfl_xor(ss, msk);
                }
                float mean = s * (1.0f / D);
                float var = ss * (1.0f / D) - mean * mean;
                float inv = rsqrtf(var + 1e-5f);
                if (row < n_rows) {
                    #pragma unroll
                    for (int n = 0; n < 8; ++n) {
                        int col = n * 16 + l15;
                        out[(size_t)row * D + col] = (vals[n][r] - mean) * inv * gv[n] + bev[n];
                    }
                }
            }
        }
    }
}

// ---------------- launch ----------------

extern "C" void kernel_launch(void* const* d_in, const int* in_sizes, int n_in,
                              void* d_out, int out_size, void* d_ws, size_t ws_size,
                              hipStream_t stream) {
    const float* x     = (const float*)d_in[0];
    const int*   idx_i = (const int*)d_in[1];
    const int*   idx_j = (const int*)d_in[2];
    const float* Wq = (const float*)d_in[3];
    const float* bq = (const float*)d_in[4];
    const float* Wk = (const float*)d_in[5];
    const float* bk = (const float*)d_in[6];
    const float* Wv = (const float*)d_in[7];
    const float* bv = (const float*)d_in[8];
    const float* Wo = (const float*)d_in[9];
    const float* bo = (const float*)d_in[10];
    const float* g1 = (const float*)d_in[11];
    const float* be1 = (const float*)d_in[12];
    const float* W1 = (const float*)d_in[13];
    const float* bb1 = (const float*)d_in[14];
    const float* W2 = (const float*)d_in[15];
    const float* bb2 = (const float*)d_in[16];
    const float* g2 = (const float*)d_in[17];
    const float* be2 = (const float*)d_in[18];

    const int N_ = in_sizes[0] / D;
    const int E_ = in_sizes[1];
    const size_t ND = (size_t)N_ * D;
    const int nb = (N_ + SCAN_CHUNK - 1) / SCAN_CHUNK;   // 49 for N=50000 (<=64 required)

    float* ws = (float*)d_ws;
    float* q = ws;                         // ND f32 (later reused as hh/hl bf16 split)
    ushort* k16 = (ushort*)(q + ND);       // ND bf16 (later reused as th)
    ushort* v16 = k16 + ND;                // ND bf16 (later reused as tl)
    int* count     = (int*)(v16 + ND);     // N
    int* row_start = count + N_;           // N+1
    int* cursor    = row_start + N_ + 1;   // N
    int* bsum      = cursor + N_;          // 64
    int* ejs       = bsum + 64;            // E
    ushort* aggh = (ushort*)(ejs + E_);    // ND bf16
    ushort* aggl = aggh + ND;              // ND bf16
    ushort* wth = aggl + ND;               // 6*128*128 bf16
    ushort* hh = (ushort*)q;
    ushort* hl = hh + ND;
    ushort* th = k16;                      // k16/v16 dead after fused_agg
    ushort* tl = v16;

    prep_w_kernel<<<6, 256, 0, stream>>>(Wq, Wk, Wv, Wo, W1, W2, wth, count, N_);
    {
        dim3 g(171, 3);
        gemm_qkv_kernel<<<g, 256, 0, stream>>>(x, wth, bq, bk, bv,
                                               idx_i, count, E_,
                                               q, k16, v16, N_);
    }
    scan_reduce_kernel<<<nb, 256, 0, stream>>>(count, bsum, N_);
    scan_write_kernel<<<nb, 256, 0, stream>>>(count, bsum, row_start, cursor, nb, N_);
    scatter_kernel<<<(E_ + 255) / 256, 256, 0, stream>>>(idx_i, idx_j, cursor, ejs, E_);
    fused_agg_kernel<<<(N_ + 3) / 4, 256, 0, stream>>>(q, k16, v16, row_start, ejs,
                                                       aggh, aggl, N_);
    gemm_oproj_kernel<<<196, 256, 0, stream>>>(aggh, aggl, x, wth + 3 * 16384,
                                               bo, g1, be1, hh, hl, N_);
    gemm_ffn1_kernel<<<196, 256, 0, stream>>>(hh, hl, wth + 4 * 16384,
                                              bb1, th, tl, N_);
    gemm_ffn2_kernel<<<196, 256, 0, stream>>>(th, tl, hh, hl, wth + 5 * 16384,
                                              bb2, g2, be2, (float*)d_out, N_);
}

// Round 19
// 244.521 us; speedup vs baseline: 1.1213x; 1.0336x over previous
//
#include <hip/hip_runtime.h>
#include <hip/hip_bf16.h>
#include <math.h>

#define D 128
#define H 8
#define DH 16
#define SCAN_CHUNK 1024

typedef __attribute__((ext_vector_type(8))) short bf16x8;
typedef __attribute__((ext_vector_type(4))) float f32x4;

__device__ __forceinline__ float bf2f(ushort u) {
    unsigned int x = ((unsigned int)u) << 16;
    float f;
    __builtin_memcpy(&f, &x, 4);
    return f;
}
__device__ __forceinline__ ushort f2bf(float f) {
    __hip_bfloat16 h = __float2bfloat16(f);
    ushort u;
    __builtin_memcpy(&u, &h, 2);
    return u;
}

// load 8 consecutive f32 and split into bf16 hi/lo fragments in-register
__device__ __forceinline__ void load_split8(const float* src, bf16x8* hi, bf16x8* lo) {
    float4 a = *(const float4*)src;
    float4 b = *(const float4*)(src + 4);
    float xs[8] = {a.x, a.y, a.z, a.w, b.x, b.y, b.z, b.w};
    short hv[8], lv[8];
    #pragma unroll
    for (int i = 0; i < 8; ++i) {
        ushort hb = f2bf(xs[i]);
        hv[i] = (short)hb;
        lv[i] = (short)f2bf(xs[i] - bf2f(hb));
    }
    *hi = (bf16x8){hv[0], hv[1], hv[2], hv[3], hv[4], hv[5], hv[6], hv[7]};
    *lo = (bf16x8){lv[0], lv[1], lv[2], lv[3], lv[4], lv[5], lv[6], lv[7]};
}

// Stage a 128x128 bf16 matrix (32KB) global -> LDS, XOR-swizzled 16B slots.
// 256-thread version: 2048 slots, 8 per thread.
#define STAGE_W(SRC, LDSBUF)                                              \
    {                                                                      \
        _Pragma("unroll")                                                  \
        for (int it_ = 0; it_ < 8; ++it_) {                                \
            int idx16_ = t + it_ * 256;                                    \
            int row_ = idx16_ >> 4, c16_ = idx16_ & 15;                    \
            int d_ = (row_ << 7) + ((c16_ ^ (row_ & 7)) << 3);             \
            *(bf16x8*)((LDSBUF) + d_) = *(const bf16x8*)((SRC) + idx16_ * 8); \
        }                                                                  \
    }

#define LOAD_A(SRCH, SRCL, BASE, AH, AL)                                   \
    _Pragma("unroll")                                                      \
    for (int kk_ = 0; kk_ < 4; ++kk_) {                                    \
        AH[kk_] = *(const bf16x8*)((SRCH) + (BASE) + kk_ * 32);            \
        AL[kk_] = *(const bf16x8*)((SRCL) + (BASE) + kk_ * 32);            \
    }

// 32-rows-per-wave MFMA tile, bf16 weights (2-term split: (Ah+Al)*Bh)
#define TILE_MFMA(AH0, AL0, AH1, AL1, WH, ACC0, ACC1)                      \
    _Pragma("unroll")                                                      \
    for (int kk = 0; kk < 4; ++kk) {                                       \
        _Pragma("unroll")                                                  \
        for (int n = 0; n < 8; ++n) {                                      \
            int rn = n * 16 + l15;                                         \
            int off = (rn << 7) + (((l4 + kk * 4) ^ (rn & 7)) << 3);       \
            bf16x8 bh = *(const bf16x8*)((WH) + off);                      \
            ACC0[n] = __builtin_amdgcn_mfma_f32_16x16x32_bf16(AH0[kk], bh, ACC0[n], 0, 0, 0); \
            ACC0[n] = __builtin_amdgcn_mfma_f32_16x16x32_bf16(AL0[kk], bh, ACC0[n], 0, 0, 0); \
            ACC1[n] = __builtin_amdgcn_mfma_f32_16x16x32_bf16(AH1[kk], bh, ACC1[n], 0, 0, 0); \
            ACC1[n] = __builtin_amdgcn_mfma_f32_16x16x32_bf16(AL1[kk], bh, ACC1[n], 0, 0, 0); \
        }                                                                  \
    }

// ---------------- prep_w: transpose 6 weight matrices (bf16) + zero count ---

__global__ __launch_bounds__(256) void prep_w_kernel(
    const float* __restrict__ w0, const float* __restrict__ w1,
    const float* __restrict__ w2, const float* __restrict__ w3,
    const float* __restrict__ w4, const float* __restrict__ w5,
    ushort* __restrict__ wth, int* __restrict__ count, int n_nodes)
{
    __shared__ __align__(16) float tile[128][132];
    const int m = blockIdx.x;
    const float* W = (m == 0) ? w0 : (m == 1) ? w1 : (m == 2) ? w2
                   : (m == 3) ? w3 : (m == 4) ? w4 : w5;
    const int t = threadIdx.x;
    // zero histogram (spread across the 6 blocks)
    for (int idx = m * 256 + t; idx < n_nodes; idx += 6 * 256) count[idx] = 0;

    const float4* wg = (const float4*)W;
    #pragma unroll
    for (int it = 0; it < 16; ++it) {
        int f4 = t + it * 256;
        int k = f4 >> 5, c4 = f4 & 31;
        *((float4*)&tile[k][c4 * 4]) = wg[f4];
    }
    __syncthreads();
    ushort* oh = wth + m * 16384;
    #pragma unroll
    for (int it = 0; it < 64; ++it) {
        int idx = t + it * 256;
        int c = idx >> 7, k = idx & 127;
        oh[idx] = f2bf(tile[k][c]);
    }
}

// ---------------- qkv: persistent bf16 W in LDS; 128-row tiles, 32 rows/wave
// grid (Gx, 3): blockIdx.y = matrix. blockIdx.y==0 blocks also run the edge
// histogram (hides atomics under the latency-bound tile loop).

__global__ __launch_bounds__(256) void gemm_qkv_kernel(
    const float* __restrict__ x,
    const ushort* __restrict__ wth,
    const float* __restrict__ bq, const float* __restrict__ bk,
    const float* __restrict__ bv,
    const int* __restrict__ idx_i, int* __restrict__ count, int n_edges,
    float* __restrict__ q, ushort* __restrict__ k16, ushort* __restrict__ v16,
    int n_rows)
{
    __shared__ __align__(16) ushort wh[16384];
    const int t = threadIdx.x;
    const int w = t >> 6, l = t & 63;
    const int l15 = l & 15, l4 = l >> 4;
    const int m = blockIdx.y;

    STAGE_W(wth + m * 16384, wh);

    // fused histogram: matrix-0 blocks cover all edges (overlaps tile loop)
    if (m == 0) {
        const int stride = gridDim.x * 256;
        for (int e = blockIdx.x * 256 + t; e < n_edges; e += stride)
            atomicAdd(&count[idx_i[e]], 1);
    }

    const float* bias = (m == 0) ? bq : (m == 1) ? bk : bv;
    float bsv[8];
    #pragma unroll
    for (int n = 0; n < 8; ++n) bsv[n] = bias[n * 16 + l15];
    __syncthreads();

    const int ntiles = (n_rows + 127) >> 7;
    for (int tile = blockIdx.x; tile < ntiles; tile += gridDim.x) {
        const int rowb = tile * 128 + w * 32;
        const size_t a0 = (size_t)(rowb + l15) * D + l4 * 8;
        bf16x8 ah0[4], al0[4], ah1[4], al1[4];
        #pragma unroll
        for (int kk = 0; kk < 4; ++kk) {
            load_split8(x + a0 + kk * 32, &ah0[kk], &al0[kk]);
            load_split8(x + a0 + 16 * D + kk * 32, &ah1[kk], &al1[kk]);
        }
        f32x4 acc0[8], acc1[8];
        #pragma unroll
        for (int n = 0; n < 8; ++n) {
            acc0[n] = (f32x4){0.f, 0.f, 0.f, 0.f};
            acc1[n] = (f32x4){0.f, 0.f, 0.f, 0.f};
        }
        TILE_MFMA(ah0, al0, ah1, al1, wh, acc0, acc1);
        #pragma unroll
        for (int n = 0; n < 8; ++n) {
            int col = n * 16 + l15;
            #pragma unroll
            for (int r = 0; r < 4; ++r) {
                int row0 = rowb + l4 * 4 + r;
                int row1 = row0 + 16;
                if (row0 < n_rows) {
                    float val = acc0[n][r] + bsv[n];
                    if (m == 0) q[(size_t)row0 * D + col] = val;
                    else if (m == 1) k16[(size_t)row0 * D + col] = f2bf(val);
                    else v16[(size_t)row0 * D + col] = f2bf(val);
                }
                if (row1 < n_rows) {
                    float val = acc1[n][r] + bsv[n];
                    if (m == 0) q[(size_t)row1 * D + col] = val;
                    else if (m == 1) k16[(size_t)row1 * D + col] = f2bf(val);
                    else v16[(size_t)row1 * D + col] = f2bf(val);
                }
            }
        }
    }
}

// ---------------- CSR build ----------------

__global__ __launch_bounds__(256) void scan_reduce_kernel(
    const int* __restrict__ count, int* __restrict__ bsum, int n)
{
    __shared__ int wsum[4];
    const int t = threadIdx.x, lane = t & 63, w = t >> 6;
    int base = blockIdx.x * SCAN_CHUNK + t * 4;
    int s = 0;
    #pragma unroll
    for (int i = 0; i < 4; ++i) {
        int idx = base + i;
        if (idx < n) s += count[idx];
    }
    #pragma unroll
    for (int off = 1; off < 64; off <<= 1) s += __shfl_xor(s, off);
    if (lane == 0) wsum[w] = s;
    __syncthreads();
    if (t == 0) bsum[blockIdx.x] = wsum[0] + wsum[1] + wsum[2] + wsum[3];
}

// scan_write derives its own block prefix from raw bsum (nb <= 64)

__global__ __launch_bounds__(256) void scan_write_kernel(
    const int* __restrict__ count, const int* __restrict__ bsum,
    int* __restrict__ row_start, int* __restrict__ cursor, int nb, int n)
{
    __shared__ int wtot[4];
    __shared__ int base_sh;
    const int t = threadIdx.x, lane = t & 63, w = t >> 6;
    if (w == 0) {   // wave 0: prefix of bsum over blocks < blockIdx.x (+ total)
        int v = (lane < nb) ? bsum[lane] : 0;
        int pre = (lane < (int)blockIdx.x) ? v : 0;
        #pragma unroll
        for (int off = 1; off < 64; off <<= 1) pre += __shfl_xor(pre, off);
        if (lane == 0) base_sh = pre;
        if (blockIdx.x == 0) {
            int tot = v;
            #pragma unroll
            for (int off = 1; off < 64; off <<= 1) tot += __shfl_xor(tot, off);
            if (lane == 0) row_start[n] = tot;
        }
    }
    int base = blockIdx.x * SCAN_CHUNK + t * 4;
    int c0 = 0, c1 = 0, c2 = 0, c3 = 0;
    if (base + 0 < n) c0 = count[base + 0];
    if (base + 1 < n) c1 = count[base + 1];
    if (base + 2 < n) c2 = count[base + 2];
    if (base + 3 < n) c3 = count[base + 3];
    int tsum = c0 + c1 + c2 + c3;
    int inc = tsum;
    #pragma unroll
    for (int off = 1; off < 64; off <<= 1) {
        int u = __shfl_up(inc, off);
        if (lane >= off) inc += u;
    }
    if (lane == 63) wtot[w] = inc;
    __syncthreads();
    int wb = 0;
    for (int i = 0; i < w; ++i) wb += wtot[i];
    int start = base_sh + wb + inc - tsum;
    if (base + 0 < n) { row_start[base + 0] = start;            cursor[base + 0] = start; }
    if (base + 1 < n) { row_start[base + 1] = start + c0;       cursor[base + 1] = start + c0; }
    if (base + 2 < n) { row_start[base + 2] = start + c0 + c1;  cursor[base + 2] = start + c0 + c1; }
    if (base + 3 < n) { row_start[base + 3] = start + c0 + c1 + c2; cursor[base + 3] = start + c0 + c1 + c2; }
}

__global__ __launch_bounds__(256) void scatter_kernel(
    const int* __restrict__ idx_i, const int* __restrict__ idx_j,
    int* __restrict__ cursor, int* __restrict__ ejs, int n_edges)
{
    int e = blockIdx.x * blockDim.x + threadIdx.x;
    if (e < n_edges) {
        int i = idx_i[e];
        int pos = atomicAdd(&cursor[i], 1);
        ejs[pos] = idx_j[e];
    }
}

// ---------------- fused per-node attention (bf16 K/V, defer-max) ------------

__global__ __launch_bounds__(256) void fused_agg_kernel(
    const float* __restrict__ q, const ushort* __restrict__ k16,
    const ushort* __restrict__ v16, const int* __restrict__ row_start,
    const int* __restrict__ ejs,
    ushort* __restrict__ aggh, ushort* __restrict__ aggl, int n_nodes)
{
    const int lane = threadIdx.x & 63;
    const int node = (blockIdx.x * blockDim.x + threadIdx.x) >> 6;
    if (node >= n_nodes) return;
    const int beg = row_start[node], end = row_start[node + 1];
    const int half = lane >> 5, sl = lane & 31;
    const int c4 = sl * 4;

    if (beg >= end) {   // empty segment: agg row = 0
        if (half == 0) {
            ((uint2*)(aggh + (size_t)node * D))[sl] = make_uint2(0u, 0u);
            ((uint2*)(aggl + (size_t)node * D))[sl] = make_uint2(0u, 0u);
        }
        return;
    }

    const float SC = 0.25f * 1.4426950408889634f;   // 1/sqrt(DH) * log2(e)
    float4 qv = *(const float4*)&q[(size_t)node * D + c4];
    qv.x *= SC; qv.y *= SC; qv.z *= SC; qv.w *= SC;
    float m = -INFINITY, l = 0.f;
    float a0 = 0.f, a1 = 0.f, a2 = 0.f, a3 = 0.f;

    int p = beg + half;
    uint2 kr0, vr0, kr1, vr1;
    if (p < end) {
        int j = ejs[p];
        kr0 = *(const uint2*)(k16 + (size_t)j * D + c4);
        vr0 = *(const uint2*)(v16 + (size_t)j * D + c4);
    }
    if (p + 2 < end) {
        int j = ejs[p + 2];
        kr1 = *(const uint2*)(k16 + (size_t)j * D + c4);
        vr1 = *(const uint2*)(v16 + (size_t)j * D + c4);
    }
    while (p < end) {
        uint2 kc = kr0, vc = vr0;
        kr0 = kr1; vr0 = vr1;
        if (p + 4 < end) {
            int j = ejs[p + 4];
            kr1 = *(const uint2*)(k16 + (size_t)j * D + c4);
            vr1 = *(const uint2*)(v16 + (size_t)j * D + c4);
        }
        float k0 = bf2f((ushort)kc.x), k1 = bf2f((ushort)(kc.x >> 16));
        float k2 = bf2f((ushort)kc.y), k3 = bf2f((ushort)(kc.y >> 16));
        float s = qv.x * k0 + qv.y * k1 + qv.z * k2 + qv.w * k3;
        s += __shfl_xor(s, 1);
        s += __shfl_xor(s, 2);
        float v0 = bf2f((ushort)vc.x), v1 = bf2f((ushort)(vc.x >> 16));
        float v2 = bf2f((ushort)vc.y), v3 = bf2f((ushort)(vc.y >> 16));
        if (__any(s > m + 8.f)) {
            float mn = fmaxf(m, s);
            float c  = exp2f(m - mn);      // exp2(-inf)=0 on first edge
            float pe = exp2f(s - mn);
            l  = l  * c + pe;
            a0 = a0 * c + pe * v0;
            a1 = a1 * c + pe * v1;
            a2 = a2 * c + pe * v2;
            a3 = a3 * c + pe * v3;
            m = mn;
        } else {
            float pe = exp2f(s - m);       // pe <= 2^8, terms referenced to m
            l += pe;
            a0 = fmaf(pe, v0, a0);
            a1 = fmaf(pe, v1, a1);
            a2 = fmaf(pe, v2, a2);
            a3 = fmaf(pe, v3, a3);
        }
        p += 2;
    }

    // merge halves
    float m2 = __shfl_xor(m, 32);
    float l2 = __shfl_xor(l, 32);
    float b0 = __shfl_xor(a0, 32);
    float b1 = __shfl_xor(a1, 32);
    float b2 = __shfl_xor(a2, 32);
    float b3 = __shfl_xor(a3, 32);
    float mm = fmaxf(m, m2);
    float cA = exp2f(m - mm);
    float cB = exp2f(m2 - mm);
    float L  = l * cA + l2 * cB;
    float A0 = a0 * cA + b0 * cB;
    float A1 = a1 * cA + b1 * cB;
    float A2 = a2 * cA + b2 * cB;
    float A3 = a3 * cA + b3 * cB;
    float invl = (L > 0.f) ? (1.0f / L) : 0.f;
    float o0 = A0 * invl, o1 = A1 * invl, o2 = A2 * invl, o3 = A3 * invl;

    ushort h0 = f2bf(o0), h1 = f2bf(o1), h2 = f2bf(o2), h3 = f2bf(o3);
    if (half == 0) {
        uint2 hv;
        hv.x = (unsigned int)h0 | ((unsigned int)h1 << 16);
        hv.y = (unsigned int)h2 | ((unsigned int)h3 << 16);
        ((uint2*)(aggh + (size_t)node * D))[sl] = hv;
    } else {
        ushort l0 = f2bf(o0 - bf2f(h0)), l1 = f2bf(o1 - bf2f(h1));
        ushort l2_ = f2bf(o2 - bf2f(h2)), l3 = f2bf(o3 - bf2f(h3));
        uint2 lv;
        lv.x = (unsigned int)l0 | ((unsigned int)l1 << 16);
        lv.y = (unsigned int)l2_ | ((unsigned int)l3 << 16);
        ((uint2*)(aggl + (size_t)node * D))[sl] = lv;
    }
}

// ---------------- oproj + LN1: persistent Wo; h = LN(x + agg@Wo + bo) -------

__global__ __launch_bounds__(256) void gemm_oproj_kernel(
    const ushort* __restrict__ aggh, const ushort* __restrict__ aggl,
    const float* __restrict__ x,
    const ushort* __restrict__ wth,
    const float* __restrict__ bo, const float* __restrict__ g1,
    const float* __restrict__ be1,
    ushort* __restrict__ hh, ushort* __restrict__ hl, int n_rows)
{
    __shared__ __align__(16) ushort wh[16384];
    const int t = threadIdx.x;
    const int w = t >> 6, l = t & 63;
    const int l15 = l & 15, l4 = l >> 4;

    STAGE_W(wth, wh);
    float bsv[8], gv[8], bev[8];
    #pragma unroll
    for (int n = 0; n < 8; ++n) {
        int col = n * 16 + l15;
        bsv[n] = bo[col]; gv[n] = g1[col]; bev[n] = be1[col];
    }
    __syncthreads();

    const int ntiles = (n_rows + 127) >> 7;
    for (int tile = blockIdx.x; tile < ntiles; tile += gridDim.x) {
        const int rowb = tile * 128 + w * 32;
        const size_t a0 = (size_t)(rowb + l15) * D + l4 * 8;
        bf16x8 ah0[4], al0[4], ah1[4], al1[4];
        LOAD_A(aggh, aggl, a0, ah0, al0);
        LOAD_A(aggh, aggl, a0 + 16 * D, ah1, al1);
        f32x4 acc0[8], acc1[8];
        #pragma unroll
        for (int n = 0; n < 8; ++n) {
            acc0[n] = (f32x4){0.f, 0.f, 0.f, 0.f};
            acc1[n] = (f32x4){0.f, 0.f, 0.f, 0.f};
        }
        TILE_MFMA(ah0, al0, ah1, al1, wh, acc0, acc1);
        // epilogue for both row groups
        #pragma unroll
        for (int g = 0; g < 2; ++g) {
            f32x4* acc = g ? acc1 : acc0;
            int rbase = rowb + g * 16;
            float vals[8][4];
            #pragma unroll
            for (int n = 0; n < 8; ++n) {
                int col = n * 16 + l15;
                #pragma unroll
                for (int r = 0; r < 4; ++r) {
                    int row = rbase + l4 * 4 + r;
                    float xr = (row < n_rows) ? x[(size_t)row * D + col] : 0.f;
                    vals[n][r] = acc[n][r] + bsv[n] + xr;
                }
            }
            #pragma unroll
            for (int r = 0; r < 4; ++r) {
                int row = rbase + l4 * 4 + r;
                float s = 0.f, ss = 0.f;
                #pragma unroll
                for (int n = 0; n < 8; ++n) { s += vals[n][r]; ss += vals[n][r] * vals[n][r]; }
                #pragma unroll
                for (int msk = 1; msk <= 8; msk <<= 1) {
                    s += __shfl_xor(s, msk);
                    ss += __shfl_xor(ss, msk);
                }
                float mean = s * (1.0f / D);
                float var = ss * (1.0f / D) - mean * mean;
                float inv = rsqrtf(var + 1e-5f);
                if (row < n_rows) {
                    #pragma unroll
                    for (int n = 0; n < 8; ++n) {
                        int col = n * 16 + l15;
                        float y = (vals[n][r] - mean) * inv * gv[n] + bev[n];
                        ushort hb = f2bf(y);
                        hh[(size_t)row * D + col] = hb;
                        hl[(size_t)row * D + col] = f2bf(y - bf2f(hb));
                    }
                }
            }
        }
    }
}

// ---------------- ffn1: t = relu(h@W1 + b1) -> th/tl (bf16 split) -----------

__global__ __launch_bounds__(256) void gemm_ffn1_kernel(
    const ushort* __restrict__ hh, const ushort* __restrict__ hl,
    const ushort* __restrict__ wth,
    const float* __restrict__ bb1,
    ushort* __restrict__ th, ushort* __restrict__ tl, int n_rows)
{
    __shared__ __align__(16) ushort wh[16384];
    const int t = threadIdx.x;
    const int w = t >> 6, l = t & 63;
    const int l15 = l & 15, l4 = l >> 4;

    STAGE_W(wth, wh);
    float bsv[8];
    #pragma unroll
    for (int n = 0; n < 8; ++n) bsv[n] = bb1[n * 16 + l15];
    __syncthreads();

    const int ntiles = (n_rows + 127) >> 7;
    for (int tile = blockIdx.x; tile < ntiles; tile += gridDim.x) {
        const int rowb = tile * 128 + w * 32;
        const size_t a0 = (size_t)(rowb + l15) * D + l4 * 8;
        bf16x8 ah0[4], al0[4], ah1[4], al1[4];
        LOAD_A(hh, hl, a0, ah0, al0);
        LOAD_A(hh, hl, a0 + 16 * D, ah1, al1);
        f32x4 acc0[8], acc1[8];
        #pragma unroll
        for (int n = 0; n < 8; ++n) {
            acc0[n] = (f32x4){0.f, 0.f, 0.f, 0.f};
            acc1[n] = (f32x4){0.f, 0.f, 0.f, 0.f};
        }
        TILE_MFMA(ah0, al0, ah1, al1, wh, acc0, acc1);
        #pragma unroll
        for (int n = 0; n < 8; ++n) {
            int col = n * 16 + l15;
            #pragma unroll
            for (int r = 0; r < 4; ++r) {
                int row0 = rowb + l4 * 4 + r;
                int row1 = row0 + 16;
                if (row0 < n_rows) {
                    float tv = fmaxf(acc0[n][r] + bsv[n], 0.f);
                    ushort hb = f2bf(tv);
                    th[(size_t)row0 * D + col] = hb;
                    tl[(size_t)row0 * D + col] = f2bf(tv - bf2f(hb));
                }
                if (row1 < n_rows) {
                    float tv = fmaxf(acc1[n][r] + bsv[n], 0.f);
                    ushort hb = f2bf(tv);
                    th[(size_t)row1 * D + col] = hb;
                    tl[(size_t)row1 * D + col] = f2bf(tv - bf2f(hb));
                }
            }
        }
    }
}

// ---------------- ffn2: out = LN(h + t@W2 + b2) -----------------------------

__global__ __launch_bounds__(256) void gemm_ffn2_kernel(
    const ushort* __restrict__ th, const ushort* __restrict__ tl,
    const ushort* __restrict__ hh, const ushort* __restrict__ hl,
    const ushort* __restrict__ wth,
    const float* __restrict__ bb2, const float* __restrict__ g2,
    const float* __restrict__ be2,
    float* __restrict__ out, int n_rows)
{
    __shared__ __align__(16) ushort wh[16384];
    const int t = threadIdx.x;
    const int w = t >> 6, l = t & 63;
    const int l15 = l & 15, l4 = l >> 4;

    STAGE_W(wth, wh);
    float bsv[8], gv[8], bev[8];
    #pragma unroll
    for (int n = 0; n < 8; ++n) {
        int col = n * 16 + l15;
        bsv[n] = bb2[col]; gv[n] = g2[col]; bev[n] = be2[col];
    }
    __syncthreads();

    const int ntiles = (n_rows + 127) >> 7;
    for (int tile = blockIdx.x; tile < ntiles; tile += gridDim.x) {
        const int rowb = tile * 128 + w * 32;
        const size_t a0 = (size_t)(rowb + l15) * D + l4 * 8;
        bf16x8 ah0[4], al0[4], ah1[4], al1[4];
        LOAD_A(th, tl, a0, ah0, al0);
        LOAD_A(th, tl, a0 + 16 * D, ah1, al1);
        f32x4 acc0[8], acc1[8];
        #pragma unroll
        for (int n = 0; n < 8; ++n) {
            acc0[n] = (f32x4){0.f, 0.f, 0.f, 0.f};
            acc1[n] = (f32x4){0.f, 0.f, 0.f, 0.f};
        }
        TILE_MFMA(ah0, al0, ah1, al1, wh, acc0, acc1);
        #pragma unroll
        for (int g = 0; g < 2; ++g) {
            f32x4* acc = g ? acc1 : acc0;
            int rbase = rowb + g * 16;
            float vals[8][4];
            #pragma unroll
            for (int n = 0; n < 8; ++n) {
                int col = n * 16 + l15;
                #pragma unroll
                for (int r = 0; r < 4; ++r) {
                    int row = rbase + l4 * 4 + r;
                    float hr = 0.f;
                    if (row < n_rows)
                        hr = bf2f(hh[(size_t)row * D + col]) + bf2f(hl[(size_t)row * D + col]);
                    vals[n][r] = acc[n][r] + bsv[n] + hr;
                }
            }
            #pragma unroll
            for (int r = 0; r < 4; ++r) {
                int row = rbase + l4 * 4 + r;
                float s = 0.f, ss = 0.f;
                #pragma unroll
                for (int n = 0; n < 8; ++n) { s += vals[n][r]; ss += vals[n][r] * vals[n][r]; }
                #pragma unroll
                for (int msk = 1; msk <= 8; msk <<= 1) {
                    s += __shfl_xor(s, msk);
                    ss += __shfl_xor(ss, msk);
                }
                float mean = s * (1.0f / D);
                float var = ss * (1.0f / D) - mean * mean;
                float inv = rsqrtf(var + 1e-5f);
                if (row < n_rows) {
                    #pragma unroll
                    for (int n = 0; n < 8; ++n) {
                        int col = n * 16 + l15;
                        out[(size_t)row * D + col] = (vals[n][r] - mean) * inv * gv[n] + bev[n];
                    }
                }
            }
        }
    }
}

// ---------------- launch ----------------

extern "C" void kernel_launch(void* const* d_in, const int* in_sizes, int n_in,
                              void* d_out, int out_size, void* d_ws, size_t ws_size,
                              hipStream_t stream) {
    const float* x     = (const float*)d_in[0];
    const int*   idx_i = (const int*)d_in[1];
    const int*   idx_j = (const int*)d_in[2];
    const float* Wq = (const float*)d_in[3];
    const float* bq = (const float*)d_in[4];
    const float* Wk = (const float*)d_in[5];
    const float* bk = (const float*)d_in[6];
    const float* Wv = (const float*)d_in[7];
    const float* bv = (const float*)d_in[8];
    const float* Wo = (const float*)d_in[9];
    const float* bo = (const float*)d_in[10];
    const float* g1 = (const float*)d_in[11];
    const float* be1 = (const float*)d_in[12];
    const float* W1 = (const float*)d_in[13];
    const float* bb1 = (const float*)d_in[14];
    const float* W2 = (const float*)d_in[15];
    const float* bb2 = (const float*)d_in[16];
    const float* g2 = (const float*)d_in[17];
    const float* be2 = (const float*)d_in[18];

    const int N_ = in_sizes[0] / D;
    const int E_ = in_sizes[1];
    const size_t ND = (size_t)N_ * D;
    const int nb = (N_ + SCAN_CHUNK - 1) / SCAN_CHUNK;   // 49 for N=50000 (<=64 required)
    const int ntiles = (N_ + 127) >> 7;                   // 391 for N=50000

    float* ws = (float*)d_ws;
    float* q = ws;                         // ND f32 (later reused as hh/hl bf16 split)
    ushort* k16 = (ushort*)(q + ND);       // ND bf16 (later reused as th)
    ushort* v16 = k16 + ND;                // ND bf16 (later reused as tl)
    int* count     = (int*)(v16 + ND);     // N
    int* row_start = count + N_;           // N+1
    int* cursor    = row_start + N_ + 1;   // N
    int* bsum      = cursor + N_;          // 64
    int* ejs       = bsum + 64;            // E
    ushort* aggh = (ushort*)(ejs + E_);    // ND bf16
    ushort* aggl = aggh + ND;              // ND bf16
    ushort* wth = aggl + ND;               // 6*128*128 bf16
    ushort* hh = (ushort*)q;
    ushort* hl = hh + ND;
    ushort* th = k16;                      // k16/v16 dead after fused_agg
    ushort* tl = v16;

    prep_w_kernel<<<6, 256, 0, stream>>>(Wq, Wk, Wv, Wo, W1, W2, wth, count, N_);
    {
        dim3 g(ntiles, 3);   // 1 tile per block; ~4.6 blocks/CU resident
        gemm_qkv_kernel<<<g, 256, 0, stream>>>(x, wth, bq, bk, bv,
                                               idx_i, count, E_,
                                               q, k16, v16, N_);
    }
    scan_reduce_kernel<<<nb, 256, 0, stream>>>(count, bsum, N_);
    scan_write_kernel<<<nb, 256, 0, stream>>>(count, bsum, row_start, cursor, nb, N_);
    scatter_kernel<<<(E_ + 255) / 256, 256, 0, stream>>>(idx_i, idx_j, cursor, ejs, E_);
    fused_agg_kernel<<<(N_ + 3) / 4, 256, 0, stream>>>(q, k16, v16, row_start, ejs,
                                                       aggh, aggl, N_);
    gemm_oproj_kernel<<<ntiles, 256, 0, stream>>>(aggh, aggl, x, wth + 3 * 16384,
                                                  bo, g1, be1, hh, hl, N_);
    gemm_ffn1_kernel<<<ntiles, 256, 0, stream>>>(hh, hl, wth + 4 * 16384,
                                                 bb1, th, tl, N_);
    gemm_ffn2_kernel<<<ntiles, 256, 0, stream>>>(th, tl, hh, hl, wth + 5 * 16384,
                                                 bb2, g2, be2, (float*)d_out, N_);
}

// Round 20
// 244.352 us; speedup vs baseline: 1.1220x; 1.0007x over previous
//
#include <hip/hip_runtime.h>
#include <hip/hip_bf16.h>
#include <math.h>

#define D 128
#define H 8
#define DH 16
#define SCAN_CHUNK 1024

typedef __attribute__((ext_vector_type(8))) short bf16x8;
typedef __attribute__((ext_vector_type(4))) float f32x4;

__device__ __forceinline__ float bf2f(ushort u) {
    unsigned int x = ((unsigned int)u) << 16;
    float f;
    __builtin_memcpy(&f, &x, 4);
    return f;
}
__device__ __forceinline__ ushort f2bf(float f) {
    __hip_bfloat16 h = __float2bfloat16(f);
    ushort u;
    __builtin_memcpy(&u, &h, 2);
    return u;
}

// load 8 consecutive f32 and split into bf16 hi/lo fragments in-register
__device__ __forceinline__ void load_split8(const float* src, bf16x8* hi, bf16x8* lo) {
    float4 a = *(const float4*)src;
    float4 b = *(const float4*)(src + 4);
    float xs[8] = {a.x, a.y, a.z, a.w, b.x, b.y, b.z, b.w};
    short hv[8], lv[8];
    #pragma unroll
    for (int i = 0; i < 8; ++i) {
        ushort hb = f2bf(xs[i]);
        hv[i] = (short)hb;
        lv[i] = (short)f2bf(xs[i] - bf2f(hb));
    }
    *hi = (bf16x8){hv[0], hv[1], hv[2], hv[3], hv[4], hv[5], hv[6], hv[7]};
    *lo = (bf16x8){lv[0], lv[1], lv[2], lv[3], lv[4], lv[5], lv[6], lv[7]};
}

// Stage a 128x128 bf16 matrix (32KB) global -> LDS, XOR-swizzled 16B slots.
// 256-thread version: 2048 slots, 8 per thread.
#define STAGE_W(SRC, LDSBUF)                                              \
    {                                                                      \
        _Pragma("unroll")                                                  \
        for (int it_ = 0; it_ < 8; ++it_) {                                \
            int idx16_ = t + it_ * 256;                                    \
            int row_ = idx16_ >> 4, c16_ = idx16_ & 15;                    \
            int d_ = (row_ << 7) + ((c16_ ^ (row_ & 7)) << 3);             \
            *(bf16x8*)((LDSBUF) + d_) = *(const bf16x8*)((SRC) + idx16_ * 8); \
        }                                                                  \
    }

#define LOAD_A(SRCH, SRCL, BASE, AH, AL)                                   \
    _Pragma("unroll")                                                      \
    for (int kk_ = 0; kk_ < 4; ++kk_) {                                    \
        AH[kk_] = *(const bf16x8*)((SRCH) + (BASE) + kk_ * 32);            \
        AL[kk_] = *(const bf16x8*)((SRCL) + (BASE) + kk_ * 32);            \
    }

// 32-rows-per-wave MFMA tile, bf16 weights (2-term split: (Ah+Al)*Bh)
#define TILE_MFMA(AH0, AL0, AH1, AL1, WH, ACC0, ACC1)                      \
    _Pragma("unroll")                                                      \
    for (int kk = 0; kk < 4; ++kk) {                                       \
        _Pragma("unroll")                                                  \
        for (int n = 0; n < 8; ++n) {                                      \
            int rn = n * 16 + l15;                                         \
            int off = (rn << 7) + (((l4 + kk * 4) ^ (rn & 7)) << 3);       \
            bf16x8 bh = *(const bf16x8*)((WH) + off);                      \
            ACC0[n] = __builtin_amdgcn_mfma_f32_16x16x32_bf16(AH0[kk], bh, ACC0[n], 0, 0, 0); \
            ACC0[n] = __builtin_amdgcn_mfma_f32_16x16x32_bf16(AL0[kk], bh, ACC0[n], 0, 0, 0); \
            ACC1[n] = __builtin_amdgcn_mfma_f32_16x16x32_bf16(AH1[kk], bh, ACC1[n], 0, 0, 0); \
            ACC1[n] = __builtin_amdgcn_mfma_f32_16x16x32_bf16(AL1[kk], bh, ACC1[n], 0, 0, 0); \
        }                                                                  \
    }

// ---------------- prep_w: transpose 6 weight matrices (bf16) + zero count ---

__global__ __launch_bounds__(256) void prep_w_kernel(
    const float* __restrict__ w0, const float* __restrict__ w1,
    const float* __restrict__ w2, const float* __restrict__ w3,
    const float* __restrict__ w4, const float* __restrict__ w5,
    ushort* __restrict__ wth, int* __restrict__ count, int n_nodes)
{
    __shared__ __align__(16) float tile[128][132];
    const int m = blockIdx.x;
    const float* W = (m == 0) ? w0 : (m == 1) ? w1 : (m == 2) ? w2
                   : (m == 3) ? w3 : (m == 4) ? w4 : w5;
    const int t = threadIdx.x;
    // zero histogram (spread across the 6 blocks)
    for (int idx = m * 256 + t; idx < n_nodes; idx += 6 * 256) count[idx] = 0;

    const float4* wg = (const float4*)W;
    #pragma unroll
    for (int it = 0; it < 16; ++it) {
        int f4 = t + it * 256;
        int k = f4 >> 5, c4 = f4 & 31;
        *((float4*)&tile[k][c4 * 4]) = wg[f4];
    }
    __syncthreads();
    ushort* oh = wth + m * 16384;
    #pragma unroll
    for (int it = 0; it < 64; ++it) {
        int idx = t + it * 256;
        int c = idx >> 7, k = idx & 127;
        oh[idx] = f2bf(tile[k][c]);
    }
}

// ---------------- qkv: persistent bf16 W in LDS; 128-row tiles, 32 rows/wave
// grid (Gx, 3): blockIdx.y = matrix. blockIdx.y==0 blocks also run the edge
// histogram (hides atomics under the latency-bound tile loop).
// q written as bf16 (qh).

__global__ __launch_bounds__(256) void gemm_qkv_kernel(
    const float* __restrict__ x,
    const ushort* __restrict__ wth,
    const float* __restrict__ bq, const float* __restrict__ bk,
    const float* __restrict__ bv,
    const int* __restrict__ idx_i, int* __restrict__ count, int n_edges,
    ushort* __restrict__ qh, ushort* __restrict__ k16, ushort* __restrict__ v16,
    int n_rows)
{
    __shared__ __align__(16) ushort wh[16384];
    const int t = threadIdx.x;
    const int w = t >> 6, l = t & 63;
    const int l15 = l & 15, l4 = l >> 4;
    const int m = blockIdx.y;

    STAGE_W(wth + m * 16384, wh);

    // fused histogram: matrix-0 blocks cover all edges (overlaps tile loop)
    if (m == 0) {
        const int stride = gridDim.x * 256;
        for (int e = blockIdx.x * 256 + t; e < n_edges; e += stride)
            atomicAdd(&count[idx_i[e]], 1);
    }

    const float* bias = (m == 0) ? bq : (m == 1) ? bk : bv;
    float bsv[8];
    #pragma unroll
    for (int n = 0; n < 8; ++n) bsv[n] = bias[n * 16 + l15];
    __syncthreads();

    const int ntiles = (n_rows + 127) >> 7;
    for (int tile = blockIdx.x; tile < ntiles; tile += gridDim.x) {
        const int rowb = tile * 128 + w * 32;
        const size_t a0 = (size_t)(rowb + l15) * D + l4 * 8;
        bf16x8 ah0[4], al0[4], ah1[4], al1[4];
        #pragma unroll
        for (int kk = 0; kk < 4; ++kk) {
            load_split8(x + a0 + kk * 32, &ah0[kk], &al0[kk]);
            load_split8(x + a0 + 16 * D + kk * 32, &ah1[kk], &al1[kk]);
        }
        f32x4 acc0[8], acc1[8];
        #pragma unroll
        for (int n = 0; n < 8; ++n) {
            acc0[n] = (f32x4){0.f, 0.f, 0.f, 0.f};
            acc1[n] = (f32x4){0.f, 0.f, 0.f, 0.f};
        }
        TILE_MFMA(ah0, al0, ah1, al1, wh, acc0, acc1);
        #pragma unroll
        for (int n = 0; n < 8; ++n) {
            int col = n * 16 + l15;
            #pragma unroll
            for (int r = 0; r < 4; ++r) {
                int row0 = rowb + l4 * 4 + r;
                int row1 = row0 + 16;
                if (row0 < n_rows) {
                    float val = acc0[n][r] + bsv[n];
                    if (m == 0) qh[(size_t)row0 * D + col] = f2bf(val);
                    else if (m == 1) k16[(size_t)row0 * D + col] = f2bf(val);
                    else v16[(size_t)row0 * D + col] = f2bf(val);
                }
                if (row1 < n_rows) {
                    float val = acc1[n][r] + bsv[n];
                    if (m == 0) qh[(size_t)row1 * D + col] = f2bf(val);
                    else if (m == 1) k16[(size_t)row1 * D + col] = f2bf(val);
                    else v16[(size_t)row1 * D + col] = f2bf(val);
                }
            }
        }
    }
}

// ---------------- CSR build ----------------

__global__ __launch_bounds__(256) void scan_reduce_kernel(
    const int* __restrict__ count, int* __restrict__ bsum, int n)
{
    __shared__ int wsum[4];
    const int t = threadIdx.x, lane = t & 63, w = t >> 6;
    int base = blockIdx.x * SCAN_CHUNK + t * 4;
    int s = 0;
    #pragma unroll
    for (int i = 0; i < 4; ++i) {
        int idx = base + i;
        if (idx < n) s += count[idx];
    }
    #pragma unroll
    for (int off = 1; off < 64; off <<= 1) s += __shfl_xor(s, off);
    if (lane == 0) wsum[w] = s;
    __syncthreads();
    if (t == 0) bsum[blockIdx.x] = wsum[0] + wsum[1] + wsum[2] + wsum[3];
}

// scan_write derives its own block prefix from raw bsum (nb <= 64)

__global__ __launch_bounds__(256) void scan_write_kernel(
    const int* __restrict__ count, const int* __restrict__ bsum,
    int* __restrict__ row_start, int* __restrict__ cursor, int nb, int n)
{
    __shared__ int wtot[4];
    __shared__ int base_sh;
    const int t = threadIdx.x, lane = t & 63, w = t >> 6;
    if (w == 0) {   // wave 0: prefix of bsum over blocks < blockIdx.x (+ total)
        int v = (lane < nb) ? bsum[lane] : 0;
        int pre = (lane < (int)blockIdx.x) ? v : 0;
        #pragma unroll
        for (int off = 1; off < 64; off <<= 1) pre += __shfl_xor(pre, off);
        if (lane == 0) base_sh = pre;
        if (blockIdx.x == 0) {
            int tot = v;
            #pragma unroll
            for (int off = 1; off < 64; off <<= 1) tot += __shfl_xor(tot, off);
            if (lane == 0) row_start[n] = tot;
        }
    }
    int base = blockIdx.x * SCAN_CHUNK + t * 4;
    int c0 = 0, c1 = 0, c2 = 0, c3 = 0;
    if (base + 0 < n) c0 = count[base + 0];
    if (base + 1 < n) c1 = count[base + 1];
    if (base + 2 < n) c2 = count[base + 2];
    if (base + 3 < n) c3 = count[base + 3];
    int tsum = c0 + c1 + c2 + c3;
    int inc = tsum;
    #pragma unroll
    for (int off = 1; off < 64; off <<= 1) {
        int u = __shfl_up(inc, off);
        if (lane >= off) inc += u;
    }
    if (lane == 63) wtot[w] = inc;
    __syncthreads();
    int wb = 0;
    for (int i = 0; i < w; ++i) wb += wtot[i];
    int start = base_sh + wb + inc - tsum;
    if (base + 0 < n) { row_start[base + 0] = start;            cursor[base + 0] = start; }
    if (base + 1 < n) { row_start[base + 1] = start + c0;       cursor[base + 1] = start + c0; }
    if (base + 2 < n) { row_start[base + 2] = start + c0 + c1;  cursor[base + 2] = start + c0 + c1; }
    if (base + 3 < n) { row_start[base + 3] = start + c0 + c1 + c2; cursor[base + 3] = start + c0 + c1 + c2; }
}

__global__ __launch_bounds__(256) void scatter_kernel(
    const int* __restrict__ idx_i, const int* __restrict__ idx_j,
    int* __restrict__ cursor, int* __restrict__ ejs, int n_edges)
{
    int e = blockIdx.x * blockDim.x + threadIdx.x;
    if (e < n_edges) {
        int i = idx_i[e];
        int pos = atomicAdd(&cursor[i], 1);
        ejs[pos] = idx_j[e];
    }
}

// ---------------- fused per-node attention (bf16 Q/K/V, quarter-wave) -------
// one wave per node; 4 groups of 16 lanes, group g handles edges beg+g+4t.
// lane covers dims [8*sl, 8*sl+8) via uint4 (16B) loads; head h = lanes
// (2h, 2h+1) -> single shfl_xor(1) reduce. defer-max softmax per group;
// two-stage merge (xor 16, 32). m init = -1e30 (finite: no inf-inf NaN).

__global__ __launch_bounds__(256) void fused_agg_kernel(
    const ushort* __restrict__ qh, const ushort* __restrict__ k16,
    const ushort* __restrict__ v16, const int* __restrict__ row_start,
    const int* __restrict__ ejs,
    ushort* __restrict__ aggh, ushort* __restrict__ aggl, int n_nodes)
{
    const int lane = threadIdx.x & 63;
    const int node = (blockIdx.x * blockDim.x + threadIdx.x) >> 6;
    if (node >= n_nodes) return;
    const int beg = row_start[node], end = row_start[node + 1];
    const int grp = lane >> 4, sl = lane & 15;
    const int c8 = sl * 8;

    if (beg >= end) {   // empty segment: agg row = 0
        if (grp == 0) ((uint4*)(aggh + (size_t)node * D))[sl] = make_uint4(0u, 0u, 0u, 0u);
        else if (grp == 1) ((uint4*)(aggl + (size_t)node * D))[sl] = make_uint4(0u, 0u, 0u, 0u);
        return;
    }

    const float SC = 0.25f * 1.4426950408889634f;   // 1/sqrt(DH) * log2(e)
    uint4 qw = *(const uint4*)(qh + (size_t)node * D + c8);
    float qv[8];
    qv[0] = bf2f((ushort)qw.x) * SC;  qv[1] = bf2f((ushort)(qw.x >> 16)) * SC;
    qv[2] = bf2f((ushort)qw.y) * SC;  qv[3] = bf2f((ushort)(qw.y >> 16)) * SC;
    qv[4] = bf2f((ushort)qw.z) * SC;  qv[5] = bf2f((ushort)(qw.z >> 16)) * SC;
    qv[6] = bf2f((ushort)qw.w) * SC;  qv[7] = bf2f((ushort)(qw.w >> 16)) * SC;

    float m = -1e30f, l = 0.f;
    float a[8];
    #pragma unroll
    for (int i = 0; i < 8; ++i) a[i] = 0.f;

    int p = beg + grp;
    uint4 kr0, vr0, kr1, vr1;
    if (p < end) {
        int j = ejs[p];
        kr0 = *(const uint4*)(k16 + (size_t)j * D + c8);
        vr0 = *(const uint4*)(v16 + (size_t)j * D + c8);
    }
    if (p + 4 < end) {
        int j = ejs[p + 4];
        kr1 = *(const uint4*)(k16 + (size_t)j * D + c8);
        vr1 = *(const uint4*)(v16 + (size_t)j * D + c8);
    }
    while (p < end) {
        uint4 kc = kr0, vc = vr0;
        kr0 = kr1; vr0 = vr1;
        if (p + 8 < end) {
            int j = ejs[p + 8];
            kr1 = *(const uint4*)(k16 + (size_t)j * D + c8);
            vr1 = *(const uint4*)(v16 + (size_t)j * D + c8);
        }
        float kf[8];
        kf[0] = bf2f((ushort)kc.x);  kf[1] = bf2f((ushort)(kc.x >> 16));
        kf[2] = bf2f((ushort)kc.y);  kf[3] = bf2f((ushort)(kc.y >> 16));
        kf[4] = bf2f((ushort)kc.z);  kf[5] = bf2f((ushort)(kc.z >> 16));
        kf[6] = bf2f((ushort)kc.w);  kf[7] = bf2f((ushort)(kc.w >> 16));
        float s = 0.f;
        #pragma unroll
        for (int i = 0; i < 8; ++i) s = fmaf(qv[i], kf[i], s);
        s += __shfl_xor(s, 1);   // head = lane pair (2h, 2h+1)
        float vf[8];
        vf[0] = bf2f((ushort)vc.x);  vf[1] = bf2f((ushort)(vc.x >> 16));
        vf[2] = bf2f((ushort)vc.y);  vf[3] = bf2f((ushort)(vc.y >> 16));
        vf[4] = bf2f((ushort)vc.z);  vf[5] = bf2f((ushort)(vc.z >> 16));
        vf[6] = bf2f((ushort)vc.w);  vf[7] = bf2f((ushort)(vc.w >> 16));
        if (__any(s > m + 8.f)) {
            // rescale path (always-correct update; taken on first edge + jumps)
            float mn = fmaxf(m, s);
            float c  = exp2f(m - mn);
            float pe = exp2f(s - mn);
            l = l * c + pe;
            #pragma unroll
            for (int i = 0; i < 8; ++i) a[i] = a[i] * c + pe * vf[i];
            m = mn;
        } else {
            float pe = exp2f(s - m);       // pe <= 2^8, terms referenced to m
            l += pe;
            #pragma unroll
            for (int i = 0; i < 8; ++i) a[i] = fmaf(pe, vf[i], a[i]);
        }
        p += 4;
    }

    // merge 4 groups: stages xor 16, xor 32 (finite m: empty groups safe)
    #pragma unroll
    for (int off = 16; off <= 32; off <<= 1) {
        float m2 = __shfl_xor(m, off);
        float l2 = __shfl_xor(l, off);
        float b[8];
        #pragma unroll
        for (int i = 0; i < 8; ++i) b[i] = __shfl_xor(a[i], off);
        float mm = fmaxf(m, m2);
        float cA = exp2f(m - mm);
        float cB = exp2f(m2 - mm);
        l = l * cA + l2 * cB;
        #pragma unroll
        for (int i = 0; i < 8; ++i) a[i] = a[i] * cA + b[i] * cB;
        m = mm;
    }
    float invl = (l > 0.f) ? (1.0f / l) : 0.f;
    float o[8];
    #pragma unroll
    for (int i = 0; i < 8; ++i) o[i] = a[i] * invl;

    ushort hb[8];
    #pragma unroll
    for (int i = 0; i < 8; ++i) hb[i] = f2bf(o[i]);
    if (grp == 0) {
        uint4 hv;
        hv.x = (unsigned int)hb[0] | ((unsigned int)hb[1] << 16);
        hv.y = (unsigned int)hb[2] | ((unsigned int)hb[3] << 16);
        hv.z = (unsigned int)hb[4] | ((unsigned int)hb[5] << 16);
        hv.w = (unsigned int)hb[6] | ((unsigned int)hb[7] << 16);
        ((uint4*)(aggh + (size_t)node * D))[sl] = hv;
    } else if (grp == 1) {
        ushort lb[8];
        #pragma unroll
        for (int i = 0; i < 8; ++i) lb[i] = f2bf(o[i] - bf2f(hb[i]));
        uint4 lv;
        lv.x = (unsigned int)lb[0] | ((unsigned int)lb[1] << 16);
        lv.y = (unsigned int)lb[2] | ((unsigned int)lb[3] << 16);
        lv.z = (unsigned int)lb[4] | ((unsigned int)lb[5] << 16);
        lv.w = (unsigned int)lb[6] | ((unsigned int)lb[7] << 16);
        ((uint4*)(aggl + (size_t)node * D))[sl] = lv;
    }
}

// ---------------- oproj + LN1: persistent Wo; h = LN(x + agg@Wo + bo) -------

__global__ __launch_bounds__(256) void gemm_oproj_kernel(
    const ushort* __restrict__ aggh, const ushort* __restrict__ aggl,
    const float* __restrict__ x,
    const ushort* __restrict__ wth,
    const float* __restrict__ bo, const float* __restrict__ g1,
    const float* __restrict__ be1,
    ushort* __restrict__ hh, ushort* __restrict__ hl, int n_rows)
{
    __shared__ __align__(16) ushort wh[16384];
    const int t = threadIdx.x;
    const int w = t >> 6, l = t & 63;
    const int l15 = l & 15, l4 = l >> 4;

    STAGE_W(wth, wh);
    float bsv[8], gv[8], bev[8];
    #pragma unroll
    for (int n = 0; n < 8; ++n) {
        int col = n * 16 + l15;
        bsv[n] = bo[col]; gv[n] = g1[col]; bev[n] = be1[col];
    }
    __syncthreads();

    const int ntiles = (n_rows + 127) >> 7;
    for (int tile = blockIdx.x; tile < ntiles; tile += gridDim.x) {
        const int rowb = tile * 128 + w * 32;
        const size_t a0 = (size_t)(rowb + l15) * D + l4 * 8;
        bf16x8 ah0[4], al0[4], ah1[4], al1[4];
        LOAD_A(aggh, aggl, a0, ah0, al0);
        LOAD_A(aggh, aggl, a0 + 16 * D, ah1, al1);
        f32x4 acc0[8], acc1[8];
        #pragma unroll
        for (int n = 0; n < 8; ++n) {
            acc0[n] = (f32x4){0.f, 0.f, 0.f, 0.f};
            acc1[n] = (f32x4){0.f, 0.f, 0.f, 0.f};
        }
        TILE_MFMA(ah0, al0, ah1, al1, wh, acc0, acc1);
        // epilogue for both row groups
        #pragma unroll
        for (int g = 0; g < 2; ++g) {
            f32x4* acc = g ? acc1 : acc0;
            int rbase = rowb + g * 16;
            float vals[8][4];
            #pragma unroll
            for (int n = 0; n < 8; ++n) {
                int col = n * 16 + l15;
                #pragma unroll
                for (int r = 0; r < 4; ++r) {
                    int row = rbase + l4 * 4 + r;
                    float xr = (row < n_rows) ? x[(size_t)row * D + col] : 0.f;
                    vals[n][r] = acc[n][r] + bsv[n] + xr;
                }
            }
            #pragma unroll
            for (int r = 0; r < 4; ++r) {
                int row = rbase + l4 * 4 + r;
                float s = 0.f, ss = 0.f;
                #pragma unroll
                for (int n = 0; n < 8; ++n) { s += vals[n][r]; ss += vals[n][r] * vals[n][r]; }
                #pragma unroll
                for (int msk = 1; msk <= 8; msk <<= 1) {
                    s += __shfl_xor(s, msk);
                    ss += __shfl_xor(ss, msk);
                }
                float mean = s * (1.0f / D);
                float var = ss * (1.0f / D) - mean * mean;
                float inv = rsqrtf(var + 1e-5f);
                if (row < n_rows) {
                    #pragma unroll
                    for (int n = 0; n < 8; ++n) {
                        int col = n * 16 + l15;
                        float y = (vals[n][r] - mean) * inv * gv[n] + bev[n];
                        ushort hb = f2bf(y);
                        hh[(size_t)row * D + col] = hb;
                        hl[(size_t)row * D + col] = f2bf(y - bf2f(hb));
                    }
                }
            }
        }
    }
}

// ---------------- ffn1: t = relu(h@W1 + b1) -> th/tl (bf16 split) -----------

__global__ __launch_bounds__(256) void gemm_ffn1_kernel(
    const ushort* __restrict__ hh, const ushort* __restrict__ hl,
    const ushort* __restrict__ wth,
    const float* __restrict__ bb1,
    ushort* __restrict__ th, ushort* __restrict__ tl, int n_rows)
{
    __shared__ __align__(16) ushort wh[16384];
    const int t = threadIdx.x;
    const int w = t >> 6, l = t & 63;
    const int l15 = l & 15, l4 = l >> 4;

    STAGE_W(wth, wh);
    float bsv[8];
    #pragma unroll
    for (int n = 0; n < 8; ++n) bsv[n] = bb1[n * 16 + l15];
    __syncthreads();

    const int ntiles = (n_rows + 127) >> 7;
    for (int tile = blockIdx.x; tile < ntiles; tile += gridDim.x) {
        const int rowb = tile * 128 + w * 32;
        const size_t a0 = (size_t)(rowb + l15) * D + l4 * 8;
        bf16x8 ah0[4], al0[4], ah1[4], al1[4];
        LOAD_A(hh, hl, a0, ah0, al0);
        LOAD_A(hh, hl, a0 + 16 * D, ah1, al1);
        f32x4 acc0[8], acc1[8];
        #pragma unroll
        for (int n = 0; n < 8; ++n) {
            acc0[n] = (f32x4){0.f, 0.f, 0.f, 0.f};
            acc1[n] = (f32x4){0.f, 0.f, 0.f, 0.f};
        }
        TILE_MFMA(ah0, al0, ah1, al1, wh, acc0, acc1);
        #pragma unroll
        for (int n = 0; n < 8; ++n) {
            int col = n * 16 + l15;
            #pragma unroll
            for (int r = 0; r < 4; ++r) {
                int row0 = rowb + l4 * 4 + r;
                int row1 = row0 + 16;
                if (row0 < n_rows) {
                    float tv = fmaxf(acc0[n][r] + bsv[n], 0.f);
                    ushort hb = f2bf(tv);
                    th[(size_t)row0 * D + col] = hb;
                    tl[(size_t)row0 * D + col] = f2bf(tv - bf2f(hb));
                }
                if (row1 < n_rows) {
                    float tv = fmaxf(acc1[n][r] + bsv[n], 0.f);
                    ushort hb = f2bf(tv);
                    th[(size_t)row1 * D + col] = hb;
                    tl[(size_t)row1 * D + col] = f2bf(tv - bf2f(hb));
                }
            }
        }
    }
}

// ---------------- ffn2: out = LN(h + t@W2 + b2) -----------------------------

__global__ __launch_bounds__(256) void gemm_ffn2_kernel(
    const ushort* __restrict__ th, const ushort* __restrict__ tl,
    const ushort* __restrict__ hh, const ushort* __restrict__ hl,
    const ushort* __restrict__ wth,
    const float* __restrict__ bb2, const float* __restrict__ g2,
    const float* __restrict__ be2,
    float* __restrict__ out, int n_rows)
{
    __shared__ __align__(16) ushort wh[16384];
    const int t = threadIdx.x;
    const int w = t >> 6, l = t & 63;
    const int l15 = l & 15, l4 = l >> 4;

    STAGE_W(wth, wh);
    float bsv[8], gv[8], bev[8];
    #pragma unroll
    for (int n = 0; n < 8; ++n) {
        int col = n * 16 + l15;
        bsv[n] = bb2[col]; gv[n] = g2[col]; bev[n] = be2[col];
    }
    __syncthreads();

    const int ntiles = (n_rows + 127) >> 7;
    for (int tile = blockIdx.x; tile < ntiles; tile += gridDim.x) {
        const int rowb = tile * 128 + w * 32;
        const size_t a0 = (size_t)(rowb + l15) * D + l4 * 8;
        bf16x8 ah0[4], al0[4], ah1[4], al1[4];
        LOAD_A(th, tl, a0, ah0, al0);
        LOAD_A(th, tl, a0 + 16 * D, ah1, al1);
        f32x4 acc0[8], acc1[8];
        #pragma unroll
        for (int n = 0; n < 8; ++n) {
            acc0[n] = (f32x4){0.f, 0.f, 0.f, 0.f};
            acc1[n] = (f32x4){0.f, 0.f, 0.f, 0.f};
        }
        TILE_MFMA(ah0, al0, ah1, al1, wh, acc0, acc1);
        #pragma unroll
        for (int g = 0; g < 2; ++g) {
            f32x4* acc = g ? acc1 : acc0;
            int rbase = rowb + g * 16;
            float vals[8][4];
            #pragma unroll
            for (int n = 0; n < 8; ++n) {
                int col = n * 16 + l15;
                #pragma unroll
                for (int r = 0; r < 4; ++r) {
                    int row = rbase + l4 * 4 + r;
                    float hr = 0.f;
                    if (row < n_rows)
                        hr = bf2f(hh[(size_t)row * D + col]) + bf2f(hl[(size_t)row * D + col]);
                    vals[n][r] = acc[n][r] + bsv[n] + hr;
                }
            }
            #pragma unroll
            for (int r = 0; r < 4; ++r) {
                int row = rbase + l4 * 4 + r;
                float s = 0.f, ss = 0.f;
                #pragma unroll
                for (int n = 0; n < 8; ++n) { s += vals[n][r]; ss += vals[n][r] * vals[n][r]; }
                #pragma unroll
                for (int msk = 1; msk <= 8; msk <<= 1) {
                    s += __shfl_xor(s, msk);
                    ss += __shfl_xor(ss, msk);
                }
                float mean = s * (1.0f / D);
                float var = ss * (1.0f / D) - mean * mean;
                float inv = rsqrtf(var + 1e-5f);
                if (row < n_rows) {
                    #pragma unroll
                    for (int n = 0; n < 8; ++n) {
                        int col = n * 16 + l15;
                        out[(size_t)row * D + col] = (vals[n][r] - mean) * inv * gv[n] + bev[n];
                    }
                }
            }
        }
    }
}

// ---------------- launch ----------------

extern "C" void kernel_launch(void* const* d_in, const int* in_sizes, int n_in,
                              void* d_out, int out_size, void* d_ws, size_t ws_size,
                              hipStream_t stream) {
    const float* x     = (const float*)d_in[0];
    const int*   idx_i = (const int*)d_in[1];
    const int*   idx_j = (const int*)d_in[2];
    const float* Wq = (const float*)d_in[3];
    const float* bq = (const float*)d_in[4];
    const float* Wk = (const float*)d_in[5];
    const float* bk = (const float*)d_in[6];
    const float* Wv = (const float*)d_in[7];
    const float* bv = (const float*)d_in[8];
    const float* Wo = (const float*)d_in[9];
    const float* bo = (const float*)d_in[10];
    const float* g1 = (const float*)d_in[11];
    const float* be1 = (const float*)d_in[12];
    const float* W1 = (const float*)d_in[13];
    const float* bb1 = (const float*)d_in[14];
    const float* W2 = (const float*)d_in[15];
    const float* bb2 = (const float*)d_in[16];
    const float* g2 = (const float*)d_in[17];
    const float* be2 = (const float*)d_in[18];

    const int N_ = in_sizes[0] / D;
    const int E_ = in_sizes[1];
    const size_t ND = (size_t)N_ * D;
    const int nb = (N_ + SCAN_CHUNK - 1) / SCAN_CHUNK;   // 49 for N=50000 (<=64 required)
    const int ntiles = (N_ + 127) >> 7;                   // 391 for N=50000

    float* ws = (float*)d_ws;
    float* qbuf = ws;                      // ND f32 region: qh bf16 now, hh/hl later
    ushort* k16 = (ushort*)(qbuf + ND);    // ND bf16 (later reused as th)
    ushort* v16 = k16 + ND;                // ND bf16 (later reused as tl)
    int* count     = (int*)(v16 + ND);     // N
    int* row_start = count + N_;           // N+1
    int* cursor    = row_start + N_ + 1;   // N
    int* bsum      = cursor + N_;          // 64
    int* ejs       = bsum + 64;            // E
    ushort* aggh = (ushort*)(ejs + E_);    // ND bf16
    ushort* aggl = aggh + ND;              // ND bf16
    ushort* wth = aggl + ND;               // 6*128*128 bf16
    ushort* qh = (ushort*)qbuf;            // ND bf16 (dead after fused_agg)
    ushort* hh = (ushort*)qbuf;            // reuses qh region after fused_agg
    ushort* hl = hh + ND;
    ushort* th = k16;                      // k16/v16 dead after fused_agg
    ushort* tl = v16;

    prep_w_kernel<<<6, 256, 0, stream>>>(Wq, Wk, Wv, Wo, W1, W2, wth, count, N_);
    {
        dim3 g(ntiles, 3);   // 1 tile per block
        gemm_qkv_kernel<<<g, 256, 0, stream>>>(x, wth, bq, bk, bv,
                                               idx_i, count, E_,
                                               qh, k16, v16, N_);
    }
    scan_reduce_kernel<<<nb, 256, 0, stream>>>(count, bsum, N_);
    scan_write_kernel<<<nb, 256, 0, stream>>>(count, bsum, row_start, cursor, nb, N_);
    scatter_kernel<<<(E_ + 255) / 256, 256, 0, stream>>>(idx_i, idx_j, cursor, ejs, E_);
    fused_agg_kernel<<<(N_ + 3) / 4, 256, 0, stream>>>(qh, k16, v16, row_start, ejs,
                                                       aggh, aggl, N_);
    gemm_oproj_kernel<<<ntiles, 256, 0, stream>>>(aggh, aggl, x, wth + 3 * 16384,
                                                  bo, g1, be1, hh, hl, N_);
    gemm_ffn1_kernel<<<ntiles, 256, 0, stream>>>(hh, hl, wth + 4 * 16384,
                                                 bb1, th, tl, N_);
    gemm_ffn2_kernel<<<ntiles, 256, 0, stream>>>(th, tl, hh, hl, wth + 5 * 16384,
                                                 bb2, g2, be2, (float*)d_out, N_);
}